// Round 16
// baseline (177.890 us; speedup 1.0000x reference)
//
#include <hip/hip_runtime.h>
#include <math.h>

#define N_ 5
#define A_ 900
#define AD_ 8
#define D_ 256
#define H_ 8
#define DH_ 32
#define K_ 300
#define NM1_ 4
#define M_ 1200   // K_*(N_-1)
#define MP_ 1216  // padded m stride for Lbuf / vhT
#define KC_ 64    // attn key chunk
#define HALF_ 600
#define NCHUNK2_ 10

typedef _Float16 f16x8 __attribute__((ext_vector_type(8)));
typedef _Float16 f16x4 __attribute__((ext_vector_type(4)));
typedef float f32x4 __attribute__((ext_vector_type(4)));

#define LOG2E_ 1.4426950408889634f

// ---------------- scores ----------------
__global__ __launch_bounds__(256) void score_kernel(const float* __restrict__ bf,
                                                    const float* __restrict__ w,
                                                    const float* __restrict__ b,
                                                    float* __restrict__ scores) {
  int wid = threadIdx.x >> 6, lane = threadIdx.x & 63;
  int row = blockIdx.x * 4 + wid;
  if (row >= N_ * A_) return;
  const float* x = bf + (long)row * D_;
  float dot = 0.f;
#pragma unroll
  for (int t = 0; t < 4; t++) dot += x[lane + 64 * t] * w[lane + 64 * t];
#pragma unroll
  for (int o = 32; o; o >>= 1) dot += __shfl_xor(dot, o, 64);
  if (lane == 0) scores[row] = dot + b[0];  // raw logit; sigmoid monotonic
}

// ---------------- top-k ----------------
__global__ __launch_bounds__(1024) void topk_kernel(const float* __restrict__ scores,
                                                    int* __restrict__ top_idx,
                                                    float* __restrict__ conf) {
  __shared__ float sc[1024];
  __shared__ int si[1024];
  int i = blockIdx.x, t = threadIdx.x;
  sc[t] = (t < A_) ? scores[i * A_ + t] : -INFINITY;
  si[t] = t;
  __syncthreads();
  for (int k = 2; k <= 1024; k <<= 1) {
    for (int j = k >> 1; j > 0; j >>= 1) {
      int ixj = t ^ j;
      if (ixj > t) {
        bool dir = ((t & k) == 0);
        float a = sc[t], b = sc[ixj];
        bool sw = dir ? (a < b) : (a > b);
        if (sw) {
          sc[t] = b; sc[ixj] = a;
          int tmp = si[t]; si[t] = si[ixj]; si[ixj] = tmp;
        }
      }
      __syncthreads();
    }
  }
  if (t < K_) {
    top_idx[i * K_ + t] = si[t];
    conf[i * K_ + t] = sc[t] > 0.0f ? 1.0f : 0.0f;
  }
}

// ---------------- tiny MLP ----------------
__global__ __launch_bounds__(256) void mlp_kernel(const float* __restrict__ tm,
                                                  const float* __restrict__ bn_g, const float* __restrict__ bn_b,
                                                  const float* __restrict__ fc1_w, const float* __restrict__ fc1_b,
                                                  const float* __restrict__ fc2_w, const float* __restrict__ fc2_b,
                                                  float* __restrict__ t_out) {
  int r = blockIdx.x;
  int t = threadIdx.x;
  __shared__ float x[20][12];
  __shared__ float y[12];
  __shared__ float hbuf[D_];
  if (t < 240) {
    int rr = t / 12, f = t % 12;
    int i = rr / NM1_, jj = rr % NM1_;
    int j = jj < i ? jj : jj + 1;
    x[rr][f] = tm[((long)(i * N_ + j) * 4 + (f / 4)) * 4 + (f % 4)];
  }
  __syncthreads();
  if (t < 12) {
    float s = 0.f;
    for (int rr = 0; rr < 20; rr++) s += x[rr][t];
    float m = s / 20.0f;
    float v = 0.f;
    for (int rr = 0; rr < 20; rr++) { float d = x[rr][t] - m; v += d * d; }
    v /= 20.0f;
    y[t] = (x[r][t] - m) * rsqrtf(v + 1e-5f) * bn_g[t] + bn_b[t];
  }
  __syncthreads();
  float acc = fc1_b[t];
#pragma unroll
  for (int f = 0; f < 12; f++) acc += y[f] * fc1_w[f * D_ + t];
  hbuf[t] = fmaxf(acc, 0.0f);
  __syncthreads();
  float acc2 = fc2_b[t];
  for (int k = 0; k < D_; k++) acc2 += hbuf[k] * fc2_w[k * D_ + t];
  t_out[r * D_ + t] = acc2;
}

// ---------------- gather (fp16 outputs, 600 blocks) ----------------
#define GKT_ 10
__global__ __launch_bounds__(256) void gather_kernel(const float* __restrict__ b_feature,
                                                     const float* __restrict__ i2j_anchor,
                                                     const int* __restrict__ top_idx,
                                                     const float* __restrict__ conf,
                                                     const float* __restrict__ anc_w,
                                                     const float* __restrict__ anc_b,
                                                     const float* __restrict__ t_mlp,
                                                     _Float16* __restrict__ key_feat16,
                                                     float* __restrict__ conf_rm,
                                                     float* __restrict__ i2j_rm,
                                                     _Float16* __restrict__ key_in16) {
  int blk = blockIdx.x;
  int i = blk / NM1_, jj = blk % NM1_;
  int j = jj < i ? jj : jj + 1;
  int k0 = blockIdx.y * GKT_;
  int c = threadIdx.x;
  __shared__ float aw[AD_][D_];
#pragma unroll
  for (int r = 0; r < AD_; r++) aw[r][c] = anc_w[r * D_ + c];
  float ab = anc_b[c];
  float tv = t_mlp[(i * NM1_ + jj) * D_ + c];
  __syncthreads();
  for (int k = k0; k < k0 + GKT_; k++) {
    int idx = top_idx[j * K_ + k];
    float cf = conf[j * K_ + k];
    const float* src = b_feature + ((long)(j * A_ + idx)) * D_;
    float val = src[c];
    long mrow = (long)i * M_ + jj * K_ + k;
    key_feat16[mrow * D_ + c] = (_Float16)val;
    const float* ap = i2j_anchor + ((long)((i * N_ + j) * A_ + idx)) * AD_;
    if (c < AD_) i2j_rm[mrow * AD_ + c] = ap[c];
    if (c == 0) conf_rm[mrow] = cf;
    float pos = ab + tv;
#pragma unroll
    for (int r = 0; r < AD_; r++) pos += ap[r] * aw[r][c];
    key_in16[mrow * D_ + c] = (_Float16)(val + pos);
  }
}

// ---------------- fused transposes ----------------
__global__ __launch_bounds__(256) void trans_kernel(const float* __restrict__ w0, const float* __restrict__ w1,
                                                    const float* __restrict__ w2, const float* __restrict__ w3,
                                                    const _Float16* __restrict__ kf,
                                                    _Float16* __restrict__ wT, _Float16* __restrict__ kT) {
  int bid = blockIdx.x;
  int t = threadIdx.x;
  if (bid < 64) {
    int y = bid >> 4, tile = bid & 15;
    const float* src = (y == 0) ? w0 : (y == 1) ? w1 : (y == 2) ? w2 : w3;
    _Float16* dst = wT + (size_t)y * D_ * D_;
    int kr = (tile >> 2) * 64, nc = (tile & 3) * 64;
    __shared__ float lds[64][65];
#pragma unroll
    for (int r = 0; r < 16; r++) {
      int row = r * 4 + (t >> 6), col = t & 63;
      lds[row][col] = src[(size_t)(kr + row) * D_ + nc + col];
    }
    __syncthreads();
#pragma unroll
    for (int r = 0; r < 16; r++) {
      int orow = r * 4 + (t >> 6), ocol = t & 63;
      dst[(size_t)(nc + orow) * D_ + kr + ocol] = (_Float16)lds[ocol][orow];
    }
  } else {
    int b = bid - 64;
    int i = b / 76, rem = b % 76;
    int m0 = (rem % 19) * 64, d0 = (rem / 19) * 64;
    __shared__ _Float16 lds2[64][66];
    const _Float16* src = kf + (size_t)i * M_ * D_;
    _Float16* dst = kT + (size_t)i * D_ * M_;
#pragma unroll
    for (int r = 0; r < 16; r++) {
      int row = r * 4 + (t >> 6), col = t & 63;
      int m = m0 + row;
      lds2[row][col] = (m < M_) ? src[(size_t)m * D_ + d0 + col] : (_Float16)0.0f;
    }
    __syncthreads();
#pragma unroll
    for (int r = 0; r < 16; r++) {
      int orow = r * 4 + (t >> 6), ocol = t & 63;
      int m = m0 + ocol;
      if (m < M_) dst[(size_t)(d0 + orow) * M_ + m] = lds2[ocol][orow];
    }
  }
}

// ---------------- fused inside mask + distance-bias table ----------------
__global__ __launch_bounds__(256) void insbias_kernel(const float* __restrict__ i2j_rm,
                                                      const float* __restrict__ conf_rm,
                                                      const float* __restrict__ ban,
                                                      _Float16* __restrict__ inside,
                                                      _Float16* __restrict__ Lbuf) {
  int i = blockIdx.x;
  int g = blockIdx.y;
  __shared__ float cx[M_], cy[M_], cz[M_], cf[M_];
  for (int m = threadIdx.x; m < M_; m += 256) {
    const float* cp = i2j_rm + ((long)i * M_ + m) * AD_;
    cx[m] = cp[0]; cy[m] = cp[1]; cz[m] = cp[2];
    cf[m] = conf_rm[(long)i * M_ + m];
  }
  __syncthreads();
#pragma unroll
  for (int r = 0; r < 4; r++) {
    int a = g * 4 + r;
    int row = i * A_ + a;
    const float* ap = ban + (long)row * AD_;
    float ax = ap[0], ay = ap[1], az = ap[2];
    float w = expf(ap[3]), l = expf(ap[4]), hh = expf(ap[5]);
    float yaw = atan2f(ap[6], ap[7]);
    float ca = fabsf(cosf(yaw)), sa = fabsf(sinf(yaw));
    float ex = 0.5f * (l * ca + w * sa);
    float ey = 0.5f * (l * sa + w * ca);
    float ez = 0.5f * hh;
    float mn0 = ax - ex, mn1 = ay - ey, mn2 = az - ez;
    float mx0 = ax + ex, mx1 = ay + ey, mx2 = az + ez;
    _Float16* ldst = Lbuf + (size_t)row * MP_;
    _Float16* idst = inside + (size_t)row * M_;
    for (int m = threadIdx.x; m < M_; m += 256) {
      float c0 = cx[m], c1 = cy[m], c2 = cz[m];
      bool ins = (c0 >= mn0) && (c0 <= mx0) && (c1 >= mn1) && (c1 <= mx1) && (c2 >= mn2) && (c2 <= mx2);
      idst[m] = ins ? (_Float16)cf[m] : (_Float16)0.0f;
      float dx = ax - c0, dy = ay - c1;
      ldst[m] = (_Float16)log1pf(sqrtf(dx * dx + dy * dy + 1e-12f));
    }
  }
}

// ---------------- shared 64x64 MFMA tile body ----------------
#define GLD_ 74
template <typename TO, bool HAS_BIAS, bool HAS_RES, bool VTRANS = false>
__device__ __forceinline__ void gemm_tile_body(
    const _Float16* __restrict__ A, int lda, int Mr,
    const _Float16* __restrict__ B, int ldb,
    const float* __restrict__ bias, const float* __restrict__ res,
    TO* __restrict__ C, int ldc,
    int m0, int n0, int k_begin, int k_end) {
  __shared__ _Float16 As[64 * GLD_];
  __shared__ _Float16 Bs[64 * GLD_];
  int tid = threadIdx.x;
  int lane = tid & 63;
  int wid = tid >> 6;
  int wr = (wid >> 1) * 32, wc = (wid & 1) * 32;
  int lr = lane & 15, lk = (lane >> 4) * 8;
  int srow = tid >> 3;
  int scol = (tid & 7) * 8;
  f16x8 aR[2], bR[2];
  f16x8 zero8 = {};
  auto loadg = [&](int kb) {
#pragma unroll
    for (int r = 0; r < 2; r++) {
      int gm = m0 + srow + r * 32;
      int gk = kb + scol;
      aR[r] = (gm < Mr && gk < k_end) ? *(const f16x8*)&A[(size_t)gm * lda + gk] : zero8;
      int gn = n0 + srow + r * 32;
      bR[r] = (gk < k_end) ? *(const f16x8*)&B[(size_t)gn * ldb + gk] : zero8;
    }
  };
  auto store_lds = [&]() {
#pragma unroll
    for (int r = 0; r < 2; r++) {
      *(f16x8*)&As[(srow + r * 32) * GLD_ + scol] = aR[r];
      *(f16x8*)&Bs[(srow + r * 32) * GLD_ + scol] = bR[r];
    }
  };
  f32x4 acc[2][2] = {};
  int niter = (k_end - k_begin + 63) >> 6;
  loadg(k_begin);
  store_lds();
  __syncthreads();
  for (int it = 0; it < niter; ++it) {
    bool more = (it + 1 < niter);
    if (more) loadg(k_begin + (it + 1) * 64);
#pragma unroll
    for (int ks = 0; ks < 2; ks++) {
      f16x8 af[2], bf[2];
#pragma unroll
      for (int mi = 0; mi < 2; mi++) af[mi] = *(const f16x8*)&As[(wr + mi * 16 + lr) * GLD_ + ks * 32 + lk];
#pragma unroll
      for (int ni = 0; ni < 2; ni++) bf[ni] = *(const f16x8*)&Bs[(wc + ni * 16 + lr) * GLD_ + ks * 32 + lk];
#pragma unroll
      for (int mi = 0; mi < 2; mi++)
#pragma unroll
        for (int ni = 0; ni < 2; ni++)
          acc[mi][ni] = __builtin_amdgcn_mfma_f32_16x16x32_f16(af[mi], bf[ni], acc[mi][ni], 0, 0, 0);
    }
    __syncthreads();
    if (more) { store_lds(); __syncthreads(); }
  }
  if (VTRANS) {
#pragma unroll
    for (int mi = 0; mi < 2; mi++)
#pragma unroll
      for (int ni = 0; ni < 2; ni++)
#pragma unroll
        for (int rr = 0; rr < 4; rr++) {
          int ml = wr + mi * 16 + (lane >> 4) * 4 + rr;
          int dl = wc + ni * 16 + lr;
          float v = acc[mi][ni][rr];
          if (HAS_BIAS) v += bias[n0 + dl];
          As[dl * 72 + ml] = (_Float16)v;
        }
    __syncthreads();
    int dl = tid >> 2, mp = (tid & 3) * 16;
    int gd = n0 + dl;
#pragma unroll
    for (int e8 = 0; e8 < 2; e8++) {
      int gm = m0 + mp + e8 * 8;
      if (gm < Mr) {
        int ii = gm / M_, mm = gm - ii * M_;
        *(f16x8*)&((_Float16*)C)[(size_t)(ii * D_ + gd) * ldc + mm] =
            *(const f16x8*)&As[dl * 72 + mp + e8 * 8];
      }
    }
    return;
  }
#pragma unroll
  for (int mi = 0; mi < 2; mi++)
#pragma unroll
    for (int ni = 0; ni < 2; ni++)
#pragma unroll
      for (int rr = 0; rr < 4; rr++) {
        int row = m0 + wr + mi * 16 + (lane >> 4) * 4 + rr;
        int col = n0 + wc + ni * 16 + lr;
        if (row < Mr) {
          float v = acc[mi][ni][rr];
          if (HAS_BIAS) v += bias[col];
          if (HAS_RES) v += res[(size_t)row * ldc + col];
          C[(size_t)row * ldc + col] = (TO)v;
        }
      }
}

// ---------------- agg GEMM split-K ----------------
__global__ __launch_bounds__(256) void agg_kernel(const _Float16* __restrict__ inside16,
                                                  const _Float16* __restrict__ kT16,
                                                  float* __restrict__ partial) {
  int i = blockIdx.z >> 2, sk = blockIdx.z & 3;
  int kb = sk * 320;
  int ke = kb + 320 < M_ ? kb + 320 : M_;
  gemm_tile_body<float, false, false>(
      inside16 + (size_t)i * A_ * M_, M_, A_,
      kT16 + (size_t)i * D_ * M_, M_,
      nullptr, nullptr,
      partial + (size_t)(sk * N_ + i) * A_ * D_, D_,
      blockIdx.x * 64, blockIdx.y * 64, kb, ke);
}

// ---------------- agg reduce + q-input prep + lam projection ----------------
__global__ __launch_bounds__(256) void agg_reduce(const float* __restrict__ partial,
                                                  const float* __restrict__ b_feature,
                                                  const float* __restrict__ anchor_embed,
                                                  const float* __restrict__ lam_w,
                                                  const float* __restrict__ lam_b,
                                                  float* __restrict__ bf_upd,
                                                  _Float16* __restrict__ qin16,
                                                  float* __restrict__ lm_rm) {
  int wid = threadIdx.x >> 6, lane = threadIdx.x & 63;
  int rg = blockIdx.x * 4 + wid;
  int d0 = lane * 4;
  float lw[4][8];
#pragma unroll
  for (int e = 0; e < 4; e++) {
#pragma unroll
    for (int h = 0; h < 8; h++) lw[e][h] = lam_w[(d0 + e) * 8 + h];
  }
  float4 s = *(const float4*)&partial[(size_t)rg * D_ + d0];
#pragma unroll
  for (int sk = 1; sk < 4; sk++) {
    float4 p = *(const float4*)&partial[((size_t)sk * N_ * A_ + rg) * D_ + d0];
    s.x += p.x; s.y += p.y; s.z += p.z; s.w += p.w;
  }
  float4 bf = *(const float4*)&b_feature[(size_t)rg * D_ + d0];
  s.x += bf.x; s.y += bf.y; s.z += bf.z; s.w += bf.w;
  *(float4*)&bf_upd[(size_t)rg * D_ + d0] = s;
  float4 ae = *(const float4*)&anchor_embed[(size_t)rg * D_ + d0];
  f16x4 q4;
  q4[0] = (_Float16)(s.x + ae.x); q4[1] = (_Float16)(s.y + ae.y);
  q4[2] = (_Float16)(s.z + ae.z); q4[3] = (_Float16)(s.w + ae.w);
  *(f16x4*)&qin16[(size_t)rg * D_ + d0] = q4;
  float sv[4] = {s.x, s.y, s.z, s.w};
  float acc[8] = {};
#pragma unroll
  for (int e = 0; e < 4; e++)
#pragma unroll
    for (int h = 0; h < 8; h++) acc[h] += sv[e] * lw[e][h];
#pragma unroll
  for (int h = 0; h < 8; h++) {
#pragma unroll
    for (int o = 32; o; o >>= 1) acc[h] += __shfl_xor(acc[h], o, 64);
  }
  if (lane == 0) {
#pragma unroll
    for (int h = 0; h < 8; h++) lm_rm[(size_t)rg * H_ + h] = acc[h] + lam_b[h];
  }
}

// ---------------- fused q/k/v projections (V written transposed) ----------------
__global__ __launch_bounds__(256) void qkv_kernel(const _Float16* __restrict__ qA,
                                                  const _Float16* __restrict__ kA,
                                                  const _Float16* __restrict__ vA,
                                                  const _Float16* __restrict__ wT,
                                                  const float* __restrict__ bq,
                                                  const float* __restrict__ bk,
                                                  const float* __restrict__ bv,
                                                  _Float16* __restrict__ qC,
                                                  _Float16* __restrict__ kC,
                                                  _Float16* __restrict__ vT) {
  int bid = blockIdx.x;
  if (bid < 284) {
    int mt = bid % 71, nt = bid / 71;
    gemm_tile_body<_Float16, true, false>(qA, D_, 4500, wT, D_, bq, nullptr, qC, D_,
                                          mt * 64, nt * 64, 0, D_);
  } else if (bid < 660) {
    int t = bid - 284;
    int mt = t % 94, nt = t / 94;
    gemm_tile_body<_Float16, true, false>(kA, D_, 6000, wT + D_ * D_, D_, bk, nullptr, kC, D_,
                                          mt * 64, nt * 64, 0, D_);
  } else {
    int t = bid - 660;
    int mt = t % 94, nt = t / 94;
    gemm_tile_body<_Float16, true, false, true>(vA, D_, 6000, wT + 2 * D_ * D_, D_, bv, nullptr, vT, MP_,
                                                mt * 64, nt * 64, 0, D_);
  }
}

// ---------------- out projection split-K x2 -> partials (reduced in LN) ----------------
__global__ __launch_bounds__(256) void outp_kernel(const _Float16* __restrict__ att16,
                                                   const _Float16* __restrict__ woT,
                                                   float* __restrict__ partial2) {
  int bid = blockIdx.x;
  int sk = bid >= 284 ? 1 : 0;
  int t = bid - sk * 284;
  int mt = t % 71, nt = t / 71;
  gemm_tile_body<float, false, false>(att16, D_, 4500, woT, D_, nullptr, nullptr,
                                      partial2 + (size_t)sk * 4500 * D_, D_,
                                      mt * 64, nt * 64, sk * 128, sk * 128 + 128);
}

// ---------------- MFMA flash attention: L direct-from-global (no Ls staging) ----------------
#define LQP_ 72
#define LKS_ 40
#define THR2_ 11.5f
__global__ __launch_bounds__(256) void attn_mfma(const _Float16* __restrict__ qh16,
                                                 const _Float16* __restrict__ kh16,
                                                 const _Float16* __restrict__ vhT,
                                                 const float* __restrict__ lm_rm,
                                                 const _Float16* __restrict__ Lbuf,
                                                 float* __restrict__ part_ms,
                                                 float* __restrict__ part_o) {
  int bid = blockIdx.x;
  int wgid = (bid & 7) * 150 + (bid >> 3);
  int ih = wgid / 30;
  int rest = wgid % 30;
  int half = rest / 15, qt = rest % 15;
  int i = ih >> 3, h = ih & 7;
  int a0 = qt * 64;
  int mbase = half * HALF_;
  int mlimit = mbase + HALF_;

  __shared__ _Float16 QP[64 * LQP_];   // 9216 B
  __shared__ _Float16 Ks[64 * LKS_];   // 5120 B
  __shared__ _Float16 Vs[32 * LQP_];   // 4608 B
  __shared__ float lmvs[64];           // total ~19.2 KB -> 8 blocks/CU

  int tid = threadIdx.x;
  int lane = tid & 63;
  int w16 = (tid >> 6) * 16;
  int lr = lane & 15;
  int lk = (lane >> 4) * 8;
  int mq = (lane >> 4) * 4;
  int srow = tid >> 2, spiece = tid & 3;
  int vrow = tid >> 3, vpc = (tid & 7) * 8;

  {
    int aq = a0 + srow;
    int a_ld = aq < A_ ? aq : A_ - 1;
    const uint4* src = (const uint4*)(qh16 + ((long)(i * A_ + a_ld) * D_ + h * DH_));
    *(uint4*)&QP[srow * LQP_ + spiece * 8] = src[spiece];
  }
  if (tid < 64) {
    int aq = a0 + tid;
    int a_ld = aq < A_ ? aq : A_ - 1;
    lmvs[tid] = lm_rm[(long)(i * A_ + a_ld) * H_ + h];
  }

  int qrow = w16 + lr;
  const _Float16* kb = kh16 + (long)i * M_ * D_ + h * DH_;
  const _Float16* vb = vhT + (size_t)(i * D_ + h * DH_) * MP_;
  // per-lane L pointer: this lane's own q-row
  const _Float16* lq;
  {
    int aq = a0 + qrow;
    int a_ld = aq < A_ ? aq : A_ - 1;
    lq = Lbuf + (size_t)(i * A_ + a_ld) * MP_ + mq;
  }

  uint4 kvR;
  f16x8 vvR;
  f16x4 lR[4];
  auto loadr = [&](int c) {
    int m0 = mbase + c * KC_;
    int mrow = m0 + srow;
    kvR = (mrow < M_) ? ((const uint4*)(kb + (long)mrow * D_))[spiece] : make_uint4(0, 0, 0, 0);
    vvR = *(const f16x8*)&vb[(size_t)vrow * MP_ + m0 + vpc];
#pragma unroll
    for (int mb = 0; mb < 4; mb++) lR[mb] = *(const f16x4*)&lq[m0 + mb * 16];
  };

  __syncthreads();  // Q + lmvs staged

  float lmv2 = lmvs[qrow] * LOG2E_;
  f16x8 qa = *(const f16x8*)&QP[qrow * LQP_ + lk];

  float m_run = -INFINITY, s_part = 0.0f;
  f32x4 oacc[2] = {};

  loadr(0);

  const float SC2 = 0.17677669529663687f * LOG2E_;

  auto chunk_body = [&](int c, bool masked) {
    int m0 = mbase + c * KC_;
    __syncthreads();
    *(uint4*)&Ks[srow * LKS_ + spiece * 8] = kvR;
    *(f16x8*)&Vs[vrow * LQP_ + vpc] = vvR;
    f16x4 lcur[4];
#pragma unroll
    for (int mb = 0; mb < 4; mb++) lcur[mb] = lR[mb];
    if (c + 1 < NCHUNK2_) loadr(c + 1);
    __syncthreads();

    f32x4 sacc[4];
#pragma unroll
    for (int mb = 0; mb < 4; mb++) {
      f16x8 kf = *(const f16x8*)&Ks[(mb * 16 + lr) * LKS_ + lk];
      sacc[mb] = __builtin_amdgcn_mfma_f32_16x16x32_f16(kf, qa, (f32x4){0.f, 0.f, 0.f, 0.f}, 0, 0, 0);
    }

    float lg[4][4];
#pragma unroll
    for (int mb = 0; mb < 4; mb++) {
#pragma unroll
      for (int rr = 0; rr < 4; rr++) {
        float v = sacc[mb][rr] * SC2 - (float)lcur[mb][rr] * lmv2;
        if (masked) {
          int mcol = m0 + mb * 16 + mq + rr;
          v = (mcol < mlimit) ? v : -INFINITY;
        }
        lg[mb][rr] = v;
      }
    }
    float cm = -INFINITY;
#pragma unroll
    for (int mb = 0; mb < 4; mb++)
#pragma unroll
      for (int rr = 0; rr < 4; rr++) cm = fmaxf(cm, lg[mb][rr]);
    cm = fmaxf(cm, __shfl_xor(cm, 16, 64));
    cm = fmaxf(cm, __shfl_xor(cm, 32, 64));

    bool upd = !__all(cm - m_run <= THR2_);
    float corr = 1.0f;
    if (upd) {
      float nm = fmaxf(m_run, cm);
      corr = exp2f(m_run - nm);
      m_run = nm;
      lmvs[qrow] = corr;
    }
    float ps = 0.0f;
#pragma unroll
    for (int mb = 0; mb < 4; mb++) {
      f16x4 p4;
#pragma unroll
      for (int rr = 0; rr < 4; rr++) {
        float p = exp2f(lg[mb][rr] - m_run);
        ps += p;
        p4[rr] = (_Float16)p;
      }
      *(f16x4*)&QP[qrow * LQP_ + mb * 16 + mq] = p4;
    }
    if (upd) {
      float4 c4 = *(const float4*)&lmvs[w16 + mq];
      s_part = s_part * corr + ps;
      oacc[0][0] *= c4.x; oacc[0][1] *= c4.y; oacc[0][2] *= c4.z; oacc[0][3] *= c4.w;
      oacc[1][0] *= c4.x; oacc[1][1] *= c4.y; oacc[1][2] *= c4.z; oacc[1][3] *= c4.w;
    } else {
      s_part += ps;
    }

#pragma unroll
    for (int ks = 0; ks < 2; ks++) {
      f16x8 pa = *(const f16x8*)&QP[(w16 + lr) * LQP_ + ks * 32 + lk];
#pragma unroll
      for (int db = 0; db < 2; db++) {
        f16x8 vf = *(const f16x8*)&Vs[(db * 16 + lr) * LQP_ + ks * 32 + lk];
        oacc[db] = __builtin_amdgcn_mfma_f32_16x16x32_f16(pa, vf, oacc[db], 0, 0, 0);
      }
    }
  };

  for (int c = 0; c < NCHUNK2_ - 1; c++) chunk_body(c, false);
  chunk_body(NCHUNK2_ - 1, true);

  float st = s_part;
  st += __shfl_xor(st, 16, 64);
  st += __shfl_xor(st, 32, 64);

  size_t base = (size_t)(half * 40 + ih) * A_;
  if (lane < 16) {
    int a = a0 + w16 + lane;
    if (a < A_) {
      part_ms[(base + a) * 2 + 0] = m_run;
      part_ms[(base + a) * 2 + 1] = st;
    }
  }
#pragma unroll
  for (int r = 0; r < 4; r++) {
    int a = a0 + w16 + mq + r;
    if (a < A_) {
      size_t rowb = base + a;
      part_o[rowb * 32 + lr] = oacc[0][r];
      part_o[rowb * 32 + 16 + lr] = oacc[1][r];
    }
  }
}

// ---------------- attention merge (exp2 domain) ----------------
__global__ __launch_bounds__(256) void attn_merge(const float* __restrict__ part_ms,
                                                  const float* __restrict__ part_o,
                                                  _Float16* __restrict__ att16) {
  int t = threadIdx.x;
  int R = blockIdx.x * 8 + (t >> 5);
  int d = t & 31;
  int ih = R / A_, a = R % A_;
  int i = ih >> 3, h = ih & 7;
  size_t r0 = (size_t)ih * A_ + a;
  size_t r1 = (size_t)(40 + ih) * A_ + a;
  float m0 = part_ms[r0 * 2], s0 = part_ms[r0 * 2 + 1];
  float m1 = part_ms[r1 * 2], s1 = part_ms[r1 * 2 + 1];
  float M = fmaxf(m0, m1);
  float e0 = exp2f(m0 - M), e1 = exp2f(m1 - M);
  float inv = 1.0f / (s0 * e0 + s1 * e1);
  float o = part_o[r0 * 32 + d] * e0 + part_o[r1 * 32 + d] * e1;
  att16[((size_t)(i * A_ + a)) * D_ + h * DH_ + d] = (_Float16)(o * inv);
}

// ---------------- LayerNorm (fused outp split-K reduce + bias + residual) ----------------
__global__ __launch_bounds__(256) void ln_kernel(const float* __restrict__ partial2,
                                                 const float* __restrict__ bo,
                                                 const float* __restrict__ resid,
                                                 const float* __restrict__ g,
                                                 const float* __restrict__ b,
                                                 float* __restrict__ out) {
  int row = blockIdx.x;
  int t = threadIdx.x;
  size_t idx = (size_t)row * D_ + t;
  float v = partial2[idx] + partial2[(size_t)4500 * D_ + idx] + bo[t] + resid[idx];
  float s = v, sq = v * v;
#pragma unroll
  for (int o = 32; o; o >>= 1) {
    s += __shfl_xor(s, o, 64);
    sq += __shfl_xor(sq, o, 64);
  }
  __shared__ float ss[4], ssq[4];
  int wid = t >> 6, lane = t & 63;
  if (lane == 0) { ss[wid] = s; ssq[wid] = sq; }
  __syncthreads();
  float ts = ss[0] + ss[1] + ss[2] + ss[3];
  float tq = ssq[0] + ssq[1] + ssq[2] + ssq[3];
  float mean = ts / (float)D_;
  float var = tq / (float)D_ - mean * mean;
  out[idx] = (v - mean) * rsqrtf(var + 1e-5f) * g[t] + b[t];
}

extern "C" void kernel_launch(void* const* d_in, const int* in_sizes, int n_in,
                              void* d_out, int out_size, void* d_ws, size_t ws_size,
                              hipStream_t stream) {
  const float* i2j_anchor   = (const float*)d_in[0];
  const float* b_anchor     = (const float*)d_in[1];
  const float* b_feature    = (const float*)d_in[2];
  const float* tm           = (const float*)d_in[3];
  const float* anchor_embed = (const float*)d_in[4];
  const float* w_roi  = (const float*)d_in[5];
  const float* b_roi  = (const float*)d_in[6];
  const float* bn_g   = (const float*)d_in[7];
  const float* bn_b   = (const float*)d_in[8];
  const float* fc1_w  = (const float*)d_in[9];
  const float* fc1_b  = (const float*)d_in[10];
  const float* fc2_w  = (const float*)d_in[11];
  const float* fc2_b  = (const float*)d_in[12];
  const float* anc_w  = (const float*)d_in[13];
  const float* anc_b  = (const float*)d_in[14];
  const float* lam_w  = (const float*)d_in[15];
  const float* lam_b  = (const float*)d_in[16];
  const float* wq = (const float*)d_in[17];
  const float* bq = (const float*)d_in[18];
  const float* wk = (const float*)d_in[19];
  const float* bk = (const float*)d_in[20];
  const float* wv = (const float*)d_in[21];
  const float* bv = (const float*)d_in[22];
  const float* wo = (const float*)d_in[23];
  const float* bo = (const float*)d_in[24];
  const float* ln_g = (const float*)d_in[25];
  const float* ln_b = (const float*)d_in[26];

  float* ws = (float*)d_ws;
  size_t off = 0;
  auto alloc = [&](size_t n) { float* p = ws + off; off += (n + 3) & ~(size_t)3; return p; };

  float* scores     = alloc(N_ * A_);
  int*   top_idx    = (int*)alloc(N_ * K_);
  float* conf       = alloc(N_ * K_);
  float* t_mlp      = alloc(20 * D_);
  float* conf_rm    = alloc((size_t)N_ * M_);
  float* i2j_rm     = alloc((size_t)N_ * M_ * AD_);
  _Float16* key_feat16 = (_Float16*)alloc((size_t)N_ * M_ * D_ / 2);
  _Float16* key_in16   = (_Float16*)alloc((size_t)N_ * M_ * D_ / 2);
  _Float16* kT16       = (_Float16*)alloc((size_t)N_ * D_ * M_ / 2);
  _Float16* inside16   = (_Float16*)alloc((size_t)N_ * A_ * M_ / 2);
  _Float16* wT16       = (_Float16*)alloc((size_t)4 * D_ * D_ / 2);
  _Float16* Lbuf16     = (_Float16*)alloc((size_t)N_ * A_ * MP_ / 2 + 16);
  float* partial    = alloc((size_t)4 * N_ * A_ * D_);
  float* bf_upd     = alloc((size_t)N_ * A_ * D_);
  _Float16* qin16   = (_Float16*)alloc((size_t)N_ * A_ * D_ / 2);
  _Float16* qh16    = (_Float16*)alloc((size_t)N_ * A_ * D_ / 2);
  _Float16* kh16    = (_Float16*)alloc((size_t)N_ * M_ * D_ / 2);
  _Float16* vhT16   = (_Float16*)alloc((size_t)N_ * D_ * MP_ / 2 + 16);
  float* lm_rm      = alloc((size_t)N_ * A_ * H_);
  _Float16* att16   = (_Float16*)alloc((size_t)N_ * A_ * D_ / 2);
  float* partial2   = alloc((size_t)2 * N_ * A_ * D_);
  float* part_ms    = alloc((size_t)2 * 40 * A_ * 2);
  float* part_o     = alloc((size_t)2 * 40 * A_ * 32);

  // 1. scores
  score_kernel<<<(N_ * A_ + 3) / 4, 256, 0, stream>>>(b_feature, w_roi, b_roi, scores);
  // 2. top-k
  topk_kernel<<<N_, 1024, 0, stream>>>(scores, top_idx, conf);
  // 3. tiny MLP
  mlp_kernel<<<20, 256, 0, stream>>>(tm, bn_g, bn_b, fc1_w, fc1_b, fc2_w, fc2_b, t_mlp);
  // 4. gather
  gather_kernel<<<dim3(N_ * NM1_, K_ / GKT_), 256, 0, stream>>>(b_feature, i2j_anchor, top_idx, conf,
                                                                anc_w, anc_b, t_mlp,
                                                                key_feat16, conf_rm, i2j_rm, key_in16);
  // 5. fused transposes
  trans_kernel<<<64 + 380, 256, 0, stream>>>(wq, wk, wv, wo, key_feat16, wT16, kT16);
  // 6. fused inside mask + bias table
  insbias_kernel<<<dim3(N_, A_ / 4), 256, 0, stream>>>(i2j_rm, conf_rm, b_anchor, inside16, Lbuf16);
  // 7. agg GEMM split-K
  agg_kernel<<<dim3(15, 4, N_ * 4), 256, 0, stream>>>(inside16, kT16, partial);
  // 8. reduce + qin + lam
  agg_reduce<<<(N_ * A_) / 4, 256, 0, stream>>>(partial, b_feature, anchor_embed, lam_w, lam_b,
                                                bf_upd, qin16, lm_rm);
  // 9. fused q/k/v projections
  qkv_kernel<<<284 + 376 + 376, 256, 0, stream>>>(qin16, key_in16, key_feat16, wT16,
                                                  bq, bk, bv, qh16, kh16, vhT16);
  // 10. attention (L direct, 8 blocks/CU)
  attn_mfma<<<1200, 256, 0, stream>>>(qh16, kh16, vhT16, lm_rm, Lbuf16, part_ms, part_o);
  // 11. merge halves
  attn_merge<<<(40 * A_) / 8, 256, 0, stream>>>(part_ms, part_o, att16);
  // 12. out projection split-K x2
  outp_kernel<<<568, 256, 0, stream>>>(att16, wT16 + 3 * D_ * D_, partial2);
  // 13. LayerNorm
  ln_kernel<<<N_ * A_, 256, 0, stream>>>(partial2, bo, bf_upd, ln_g, ln_b, (float*)d_out);
}

// Round 18
// 173.621 us; speedup vs baseline: 1.0246x; 1.0246x over previous
//
#include <hip/hip_runtime.h>
#include <math.h>

#define N_ 5
#define A_ 900
#define AD_ 8
#define D_ 256
#define H_ 8
#define DH_ 32
#define K_ 300
#define NM1_ 4
#define M_ 1200   // K_*(N_-1)
#define MP_ 1216  // padded m stride for Lbuf / vhT
#define KC_ 64    // attn key chunk
#define HALF_ 600
#define NCHUNK2_ 10
#define SCOREB_ 1125  // ceil(N_*A_/4) blocks for the score phase

typedef _Float16 f16x8 __attribute__((ext_vector_type(8)));
typedef _Float16 f16x4 __attribute__((ext_vector_type(4)));
typedef float f32x4 __attribute__((ext_vector_type(4)));

#define LOG2E_ 1.4426950408889634f

// ---------------- fused scores (blocks 0..1124) + tiny MLP (blocks 1125..1144) ----------------
__global__ __launch_bounds__(256) void scoremlp_kernel(const float* __restrict__ bf,
                                                       const float* __restrict__ w,
                                                       const float* __restrict__ b,
                                                       const float* __restrict__ tm,
                                                       const float* __restrict__ bn_g, const float* __restrict__ bn_b,
                                                       const float* __restrict__ fc1_w, const float* __restrict__ fc1_b,
                                                       const float* __restrict__ fc2_w, const float* __restrict__ fc2_b,
                                                       float* __restrict__ scores,
                                                       float* __restrict__ t_out) {
  int bid = blockIdx.x;
  int t = threadIdx.x;
  if (bid < SCOREB_) {
    int wid = t >> 6, lane = t & 63;
    int row = bid * 4 + wid;
    if (row >= N_ * A_) return;
    const float* x = bf + (long)row * D_;
    float dot = 0.f;
#pragma unroll
    for (int e = 0; e < 4; e++) dot += x[lane + 64 * e] * w[lane + 64 * e];
#pragma unroll
    for (int o = 32; o; o >>= 1) dot += __shfl_xor(dot, o, 64);
    if (lane == 0) scores[row] = dot + b[0];  // raw logit; sigmoid monotonic
  } else {
    int r = bid - SCOREB_;
    __shared__ float x2[20][12];
    __shared__ float y2[12];
    __shared__ float hbuf[D_];
    if (t < 240) {
      int rr = t / 12, f = t % 12;
      int i = rr / NM1_, jj = rr % NM1_;
      int j = jj < i ? jj : jj + 1;
      x2[rr][f] = tm[((long)(i * N_ + j) * 4 + (f / 4)) * 4 + (f % 4)];
    }
    __syncthreads();
    if (t < 12) {
      float s = 0.f;
      for (int rr = 0; rr < 20; rr++) s += x2[rr][t];
      float m = s / 20.0f;
      float v = 0.f;
      for (int rr = 0; rr < 20; rr++) { float d = x2[rr][t] - m; v += d * d; }
      v /= 20.0f;
      y2[t] = (x2[r][t] - m) * rsqrtf(v + 1e-5f) * bn_g[t] + bn_b[t];
    }
    __syncthreads();
    float acc = fc1_b[t];
#pragma unroll
    for (int f = 0; f < 12; f++) acc += y2[f] * fc1_w[f * D_ + t];
    hbuf[t] = fmaxf(acc, 0.0f);
    __syncthreads();
    float acc2 = fc2_b[t];
    for (int k = 0; k < D_; k++) acc2 += hbuf[k] * fc2_w[k * D_ + t];
    t_out[r * D_ + t] = acc2;
  }
}

// ---------------- top-k ----------------
__global__ __launch_bounds__(1024) void topk_kernel(const float* __restrict__ scores,
                                                    int* __restrict__ top_idx,
                                                    float* __restrict__ conf) {
  __shared__ float sc[1024];
  __shared__ int si[1024];
  int i = blockIdx.x, t = threadIdx.x;
  sc[t] = (t < A_) ? scores[i * A_ + t] : -INFINITY;
  si[t] = t;
  __syncthreads();
  for (int k = 2; k <= 1024; k <<= 1) {
    for (int j = k >> 1; j > 0; j >>= 1) {
      int ixj = t ^ j;
      if (ixj > t) {
        bool dir = ((t & k) == 0);
        float a = sc[t], b = sc[ixj];
        bool sw = dir ? (a < b) : (a > b);
        if (sw) {
          sc[t] = b; sc[ixj] = a;
          int tmp = si[t]; si[t] = si[ixj]; si[ixj] = tmp;
        }
      }
      __syncthreads();
    }
  }
  if (t < K_) {
    top_idx[i * K_ + t] = si[t];
    conf[i * K_ + t] = sc[t] > 0.0f ? 1.0f : 0.0f;
  }
}

// ---------------- gather (fp16 outputs, 600 blocks) ----------------
#define GKT_ 10
__global__ __launch_bounds__(256) void gather_kernel(const float* __restrict__ b_feature,
                                                     const float* __restrict__ i2j_anchor,
                                                     const int* __restrict__ top_idx,
                                                     const float* __restrict__ conf,
                                                     const float* __restrict__ anc_w,
                                                     const float* __restrict__ anc_b,
                                                     const float* __restrict__ t_mlp,
                                                     _Float16* __restrict__ key_feat16,
                                                     float* __restrict__ conf_rm,
                                                     float* __restrict__ i2j_rm,
                                                     _Float16* __restrict__ key_in16) {
  int blk = blockIdx.x;
  int i = blk / NM1_, jj = blk % NM1_;
  int j = jj < i ? jj : jj + 1;
  int k0 = blockIdx.y * GKT_;
  int c = threadIdx.x;
  __shared__ float aw[AD_][D_];
#pragma unroll
  for (int r = 0; r < AD_; r++) aw[r][c] = anc_w[r * D_ + c];
  float ab = anc_b[c];
  float tv = t_mlp[(i * NM1_ + jj) * D_ + c];
  __syncthreads();
  for (int k = k0; k < k0 + GKT_; k++) {
    int idx = top_idx[j * K_ + k];
    float cf = conf[j * K_ + k];
    const float* src = b_feature + ((long)(j * A_ + idx)) * D_;
    float val = src[c];
    long mrow = (long)i * M_ + jj * K_ + k;
    key_feat16[mrow * D_ + c] = (_Float16)val;
    const float* ap = i2j_anchor + ((long)((i * N_ + j) * A_ + idx)) * AD_;
    if (c < AD_) i2j_rm[mrow * AD_ + c] = ap[c];
    if (c == 0) conf_rm[mrow] = cf;
    float pos = ab + tv;
#pragma unroll
    for (int r = 0; r < AD_; r++) pos += ap[r] * aw[r][c];
    key_in16[mrow * D_ + c] = (_Float16)(val + pos);
  }
}

// ---------------- fused transposes ----------------
__global__ __launch_bounds__(256) void trans_kernel(const float* __restrict__ w0, const float* __restrict__ w1,
                                                    const float* __restrict__ w2, const float* __restrict__ w3,
                                                    const _Float16* __restrict__ kf,
                                                    _Float16* __restrict__ wT, _Float16* __restrict__ kT) {
  int bid = blockIdx.x;
  int t = threadIdx.x;
  if (bid < 64) {
    int y = bid >> 4, tile = bid & 15;
    const float* src = (y == 0) ? w0 : (y == 1) ? w1 : (y == 2) ? w2 : w3;
    _Float16* dst = wT + (size_t)y * D_ * D_;
    int kr = (tile >> 2) * 64, nc = (tile & 3) * 64;
    __shared__ float lds[64][65];
#pragma unroll
    for (int r = 0; r < 16; r++) {
      int row = r * 4 + (t >> 6), col = t & 63;
      lds[row][col] = src[(size_t)(kr + row) * D_ + nc + col];
    }
    __syncthreads();
#pragma unroll
    for (int r = 0; r < 16; r++) {
      int orow = r * 4 + (t >> 6), ocol = t & 63;
      dst[(size_t)(nc + orow) * D_ + kr + ocol] = (_Float16)lds[ocol][orow];
    }
  } else {
    int b = bid - 64;
    int i = b / 76, rem = b % 76;
    int m0 = (rem % 19) * 64, d0 = (rem / 19) * 64;
    __shared__ _Float16 lds2[64][66];
    const _Float16* src = kf + (size_t)i * M_ * D_;
    _Float16* dst = kT + (size_t)i * D_ * M_;
#pragma unroll
    for (int r = 0; r < 16; r++) {
      int row = r * 4 + (t >> 6), col = t & 63;
      int m = m0 + row;
      lds2[row][col] = (m < M_) ? src[(size_t)m * D_ + d0 + col] : (_Float16)0.0f;
    }
    __syncthreads();
#pragma unroll
    for (int r = 0; r < 16; r++) {
      int orow = r * 4 + (t >> 6), ocol = t & 63;
      int m = m0 + ocol;
      if (m < M_) dst[(size_t)(d0 + orow) * M_ + m] = lds2[ocol][orow];
    }
  }
}

// ---------------- fused inside mask + distance-bias table ----------------
__global__ __launch_bounds__(256) void insbias_kernel(const float* __restrict__ i2j_rm,
                                                      const float* __restrict__ conf_rm,
                                                      const float* __restrict__ ban,
                                                      _Float16* __restrict__ inside,
                                                      _Float16* __restrict__ Lbuf) {
  int i = blockIdx.x;
  int g = blockIdx.y;
  __shared__ float cx[M_], cy[M_], cz[M_], cf[M_];
  for (int m = threadIdx.x; m < M_; m += 256) {
    const float* cp = i2j_rm + ((long)i * M_ + m) * AD_;
    cx[m] = cp[0]; cy[m] = cp[1]; cz[m] = cp[2];
    cf[m] = conf_rm[(long)i * M_ + m];
  }
  __syncthreads();
#pragma unroll
  for (int r = 0; r < 4; r++) {
    int a = g * 4 + r;
    int row = i * A_ + a;
    const float* ap = ban + (long)row * AD_;
    float ax = ap[0], ay = ap[1], az = ap[2];
    float w = expf(ap[3]), l = expf(ap[4]), hh = expf(ap[5]);
    float yaw = atan2f(ap[6], ap[7]);
    float ca = fabsf(cosf(yaw)), sa = fabsf(sinf(yaw));
    float ex = 0.5f * (l * ca + w * sa);
    float ey = 0.5f * (l * sa + w * ca);
    float ez = 0.5f * hh;
    float mn0 = ax - ex, mn1 = ay - ey, mn2 = az - ez;
    float mx0 = ax + ex, mx1 = ay + ey, mx2 = az + ez;
    _Float16* ldst = Lbuf + (size_t)row * MP_;
    _Float16* idst = inside + (size_t)row * M_;
    for (int m = threadIdx.x; m < M_; m += 256) {
      float c0 = cx[m], c1 = cy[m], c2 = cz[m];
      bool ins = (c0 >= mn0) && (c0 <= mx0) && (c1 >= mn1) && (c1 <= mx1) && (c2 >= mn2) && (c2 <= mx2);
      idst[m] = ins ? (_Float16)cf[m] : (_Float16)0.0f;
      float dx = ax - c0, dy = ay - c1;
      ldst[m] = (_Float16)log1pf(sqrtf(dx * dx + dy * dy + 1e-12f));
    }
  }
}

// ---------------- shared 64x64 MFMA tile body ----------------
#define GLD_ 74
template <typename TO, bool HAS_BIAS, bool HAS_RES, bool VTRANS = false>
__device__ __forceinline__ void gemm_tile_body(
    const _Float16* __restrict__ A, int lda, int Mr,
    const _Float16* __restrict__ B, int ldb,
    const float* __restrict__ bias, const float* __restrict__ res,
    TO* __restrict__ C, int ldc,
    int m0, int n0, int k_begin, int k_end) {
  __shared__ _Float16 As[64 * GLD_];
  __shared__ _Float16 Bs[64 * GLD_];
  int tid = threadIdx.x;
  int lane = tid & 63;
  int wid = tid >> 6;
  int wr = (wid >> 1) * 32, wc = (wid & 1) * 32;
  int lr = lane & 15, lk = (lane >> 4) * 8;
  int srow = tid >> 3;
  int scol = (tid & 7) * 8;
  f16x8 aR[2], bR[2];
  f16x8 zero8 = {};
  auto loadg = [&](int kb) {
#pragma unroll
    for (int r = 0; r < 2; r++) {
      int gm = m0 + srow + r * 32;
      int gk = kb + scol;
      aR[r] = (gm < Mr && gk < k_end) ? *(const f16x8*)&A[(size_t)gm * lda + gk] : zero8;
      int gn = n0 + srow + r * 32;
      bR[r] = (gk < k_end) ? *(const f16x8*)&B[(size_t)gn * ldb + gk] : zero8;
    }
  };
  auto store_lds = [&]() {
#pragma unroll
    for (int r = 0; r < 2; r++) {
      *(f16x8*)&As[(srow + r * 32) * GLD_ + scol] = aR[r];
      *(f16x8*)&Bs[(srow + r * 32) * GLD_ + scol] = bR[r];
    }
  };
  f32x4 acc[2][2] = {};
  int niter = (k_end - k_begin + 63) >> 6;
  loadg(k_begin);
  store_lds();
  __syncthreads();
  for (int it = 0; it < niter; ++it) {
    bool more = (it + 1 < niter);
    if (more) loadg(k_begin + (it + 1) * 64);
#pragma unroll
    for (int ks = 0; ks < 2; ks++) {
      f16x8 af[2], bf[2];
#pragma unroll
      for (int mi = 0; mi < 2; mi++) af[mi] = *(const f16x8*)&As[(wr + mi * 16 + lr) * GLD_ + ks * 32 + lk];
#pragma unroll
      for (int ni = 0; ni < 2; ni++) bf[ni] = *(const f16x8*)&Bs[(wc + ni * 16 + lr) * GLD_ + ks * 32 + lk];
#pragma unroll
      for (int mi = 0; mi < 2; mi++)
#pragma unroll
        for (int ni = 0; ni < 2; ni++)
          acc[mi][ni] = __builtin_amdgcn_mfma_f32_16x16x32_f16(af[mi], bf[ni], acc[mi][ni], 0, 0, 0);
    }
    __syncthreads();
    if (more) { store_lds(); __syncthreads(); }
  }
  if (VTRANS) {
#pragma unroll
    for (int mi = 0; mi < 2; mi++)
#pragma unroll
      for (int ni = 0; ni < 2; ni++)
#pragma unroll
        for (int rr = 0; rr < 4; rr++) {
          int ml = wr + mi * 16 + (lane >> 4) * 4 + rr;
          int dl = wc + ni * 16 + lr;
          float v = acc[mi][ni][rr];
          if (HAS_BIAS) v += bias[n0 + dl];
          As[dl * 72 + ml] = (_Float16)v;
        }
    __syncthreads();
    int dl = tid >> 2, mp = (tid & 3) * 16;
    int gd = n0 + dl;
#pragma unroll
    for (int e8 = 0; e8 < 2; e8++) {
      int gm = m0 + mp + e8 * 8;
      if (gm < Mr) {
        int ii = gm / M_, mm = gm - ii * M_;
        *(f16x8*)&((_Float16*)C)[(size_t)(ii * D_ + gd) * ldc + mm] =
            *(const f16x8*)&As[dl * 72 + mp + e8 * 8];
      }
    }
    return;
  }
#pragma unroll
  for (int mi = 0; mi < 2; mi++)
#pragma unroll
    for (int ni = 0; ni < 2; ni++)
#pragma unroll
      for (int rr = 0; rr < 4; rr++) {
        int row = m0 + wr + mi * 16 + (lane >> 4) * 4 + rr;
        int col = n0 + wc + ni * 16 + lr;
        if (row < Mr) {
          float v = acc[mi][ni][rr];
          if (HAS_BIAS) v += bias[col];
          if (HAS_RES) v += res[(size_t)row * ldc + col];
          C[(size_t)row * ldc + col] = (TO)v;
        }
      }
}

// ---------------- agg GEMM split-K ----------------
__global__ __launch_bounds__(256) void agg_kernel(const _Float16* __restrict__ inside16,
                                                  const _Float16* __restrict__ kT16,
                                                  float* __restrict__ partial) {
  int i = blockIdx.z >> 2, sk = blockIdx.z & 3;
  int kb = sk * 320;
  int ke = kb + 320 < M_ ? kb + 320 : M_;
  gemm_tile_body<float, false, false>(
      inside16 + (size_t)i * A_ * M_, M_, A_,
      kT16 + (size_t)i * D_ * M_, M_,
      nullptr, nullptr,
      partial + (size_t)(sk * N_ + i) * A_ * D_, D_,
      blockIdx.x * 64, blockIdx.y * 64, kb, ke);
}

// ---------------- agg reduce + q-input prep + lam projection ----------------
__global__ __launch_bounds__(256) void agg_reduce(const float* __restrict__ partial,
                                                  const float* __restrict__ b_feature,
                                                  const float* __restrict__ anchor_embed,
                                                  const float* __restrict__ lam_w,
                                                  const float* __restrict__ lam_b,
                                                  float* __restrict__ bf_upd,
                                                  _Float16* __restrict__ qin16,
                                                  float* __restrict__ lm_rm) {
  int wid = threadIdx.x >> 6, lane = threadIdx.x & 63;
  int rg = blockIdx.x * 4 + wid;
  int d0 = lane * 4;
  float lw[4][8];
#pragma unroll
  for (int e = 0; e < 4; e++) {
#pragma unroll
    for (int h = 0; h < 8; h++) lw[e][h] = lam_w[(d0 + e) * 8 + h];
  }
  float4 s = *(const float4*)&partial[(size_t)rg * D_ + d0];
#pragma unroll
  for (int sk = 1; sk < 4; sk++) {
    float4 p = *(const float4*)&partial[((size_t)sk * N_ * A_ + rg) * D_ + d0];
    s.x += p.x; s.y += p.y; s.z += p.z; s.w += p.w;
  }
  float4 bf = *(const float4*)&b_feature[(size_t)rg * D_ + d0];
  s.x += bf.x; s.y += bf.y; s.z += bf.z; s.w += bf.w;
  *(float4*)&bf_upd[(size_t)rg * D_ + d0] = s;
  float4 ae = *(const float4*)&anchor_embed[(size_t)rg * D_ + d0];
  f16x4 q4;
  q4[0] = (_Float16)(s.x + ae.x); q4[1] = (_Float16)(s.y + ae.y);
  q4[2] = (_Float16)(s.z + ae.z); q4[3] = (_Float16)(s.w + ae.w);
  *(f16x4*)&qin16[(size_t)rg * D_ + d0] = q4;
  float sv[4] = {s.x, s.y, s.z, s.w};
  float acc[8] = {};
#pragma unroll
  for (int e = 0; e < 4; e++)
#pragma unroll
    for (int h = 0; h < 8; h++) acc[h] += sv[e] * lw[e][h];
#pragma unroll
  for (int h = 0; h < 8; h++) {
#pragma unroll
    for (int o = 32; o; o >>= 1) acc[h] += __shfl_xor(acc[h], o, 64);
  }
  if (lane == 0) {
#pragma unroll
    for (int h = 0; h < 8; h++) lm_rm[(size_t)rg * H_ + h] = acc[h] + lam_b[h];
  }
}

// ---------------- fused q/k/v projections (V written transposed) ----------------
__global__ __launch_bounds__(256) void qkv_kernel(const _Float16* __restrict__ qA,
                                                  const _Float16* __restrict__ kA,
                                                  const _Float16* __restrict__ vA,
                                                  const _Float16* __restrict__ wT,
                                                  const float* __restrict__ bq,
                                                  const float* __restrict__ bk,
                                                  const float* __restrict__ bv,
                                                  _Float16* __restrict__ qC,
                                                  _Float16* __restrict__ kC,
                                                  _Float16* __restrict__ vT) {
  int bid = blockIdx.x;
  if (bid < 284) {
    int mt = bid % 71, nt = bid / 71;
    gemm_tile_body<_Float16, true, false>(qA, D_, 4500, wT, D_, bq, nullptr, qC, D_,
                                          mt * 64, nt * 64, 0, D_);
  } else if (bid < 660) {
    int t = bid - 284;
    int mt = t % 94, nt = t / 94;
    gemm_tile_body<_Float16, true, false>(kA, D_, 6000, wT + D_ * D_, D_, bk, nullptr, kC, D_,
                                          mt * 64, nt * 64, 0, D_);
  } else {
    int t = bid - 660;
    int mt = t % 94, nt = t / 94;
    gemm_tile_body<_Float16, true, false, true>(vA, D_, 6000, wT + 2 * D_ * D_, D_, bv, nullptr, vT, MP_,
                                                mt * 64, nt * 64, 0, D_);
  }
}

// ---------------- out projection split-K x2 -> partials (reduced in LN) ----------------
__global__ __launch_bounds__(256) void outp_kernel(const _Float16* __restrict__ att16,
                                                   const _Float16* __restrict__ woT,
                                                   float* __restrict__ partial2) {
  int bid = blockIdx.x;
  int sk = bid >= 284 ? 1 : 0;
  int t = bid - sk * 284;
  int mt = t % 71, nt = t / 71;
  gemm_tile_body<float, false, false>(att16, D_, 4500, woT, D_, nullptr, nullptr,
                                      partial2 + (size_t)sk * 4500 * D_, D_,
                                      mt * 64, nt * 64, sk * 128, sk * 128 + 128);
}

// ---------------- MFMA flash attention: double-buffered LDS, 1 barrier/chunk ----------------
#define LQP_ 72
#define LKS_ 40
#define THR2_ 11.5f
__global__ __launch_bounds__(256) void attn_mfma(const _Float16* __restrict__ qh16,
                                                 const _Float16* __restrict__ kh16,
                                                 const _Float16* __restrict__ vhT,
                                                 const float* __restrict__ lm_rm,
                                                 const _Float16* __restrict__ Lbuf,
                                                 float* __restrict__ part_ms,
                                                 float* __restrict__ part_o) {
  int bid = blockIdx.x;
  int wgid = (bid & 7) * 150 + (bid >> 3);
  int ih = wgid / 30;
  int rest = wgid % 30;
  int half = rest / 15, qt = rest % 15;
  int i = ih >> 3, h = ih & 7;
  int a0 = qt * 64;
  int mbase = half * HALF_;
  int mlimit = mbase + HALF_;

  __shared__ _Float16 QP[64 * LQP_];
  __shared__ _Float16 Ks[2][64 * LKS_];
  __shared__ _Float16 Vs[2][32 * LQP_];
  __shared__ float lmvs[64];

  int tid = threadIdx.x;
  int lane = tid & 63;
  int w16 = (tid >> 6) * 16;
  int lr = lane & 15;
  int lk = (lane >> 4) * 8;
  int mq = (lane >> 4) * 4;
  int srow = tid >> 2, spiece = tid & 3;
  int vrow = tid >> 3, vpc = (tid & 7) * 8;

  {
    int aq = a0 + srow;
    int a_ld = aq < A_ ? aq : A_ - 1;
    const uint4* src = (const uint4*)(qh16 + ((long)(i * A_ + a_ld) * D_ + h * DH_));
    *(uint4*)&QP[srow * LQP_ + spiece * 8] = src[spiece];
  }
  if (tid < 64) {
    int aq = a0 + tid;
    int a_ld = aq < A_ ? aq : A_ - 1;
    lmvs[tid] = lm_rm[(long)(i * A_ + a_ld) * H_ + h];
  }

  int qrow = w16 + lr;
  const _Float16* kb = kh16 + (long)i * M_ * D_ + h * DH_;
  const _Float16* vb = vhT + (size_t)(i * D_ + h * DH_) * MP_;
  const _Float16* lq;
  {
    int aq = a0 + qrow;
    int a_ld = aq < A_ ? aq : A_ - 1;
    lq = Lbuf + (size_t)(i * A_ + a_ld) * MP_ + mq;
  }

  uint4 kvR;
  f16x8 vvR;
  f16x4 lR[4];
  auto loadr = [&](int c) {
    int m0 = mbase + c * KC_;
    int mrow = m0 + srow;
    kvR = (mrow < M_) ? ((const uint4*)(kb + (long)mrow * D_))[spiece] : make_uint4(0, 0, 0, 0);
    vvR = *(const f16x8*)&vb[(size_t)vrow * MP_ + m0 + vpc];
#pragma unroll
    for (int mb = 0; mb < 4; mb++) lR[mb] = *(const f16x4*)&lq[m0 + mb * 16];
  };

  __syncthreads();  // Q + lmvs staged

  float lmv2 = lmvs[qrow] * LOG2E_;
  f16x8 qa = *(const f16x8*)&QP[qrow * LQP_ + lk];

  float m_run = -INFINITY, s_part = 0.0f;
  f32x4 oacc[2] = {};

  loadr(0);

  const float SC2 = 0.17677669529663687f * LOG2E_;

  // 1-barrier/chunk: stores to buf[c&1] precede the barrier; compute(c) reads buf[c&1].
  // Barrier spacing keeps waves <=1 iter apart, so stores to buf[X] only overlap
  // reads of buf[X^1] -> race-free.
  auto chunk_body = [&](int c, bool masked) {
    int m0 = mbase + c * KC_;
    int cur = c & 1;
    *(uint4*)&Ks[cur][srow * LKS_ + spiece * 8] = kvR;
    *(f16x8*)&Vs[cur][vrow * LQP_ + vpc] = vvR;
    f16x4 lcur[4];
#pragma unroll
    for (int mb = 0; mb < 4; mb++) lcur[mb] = lR[mb];
    if (c + 1 < NCHUNK2_) loadr(c + 1);
    __syncthreads();

    f32x4 sacc[4];
#pragma unroll
    for (int mb = 0; mb < 4; mb++) {
      f16x8 kf = *(const f16x8*)&Ks[cur][(mb * 16 + lr) * LKS_ + lk];
      sacc[mb] = __builtin_amdgcn_mfma_f32_16x16x32_f16(kf, qa, (f32x4){0.f, 0.f, 0.f, 0.f}, 0, 0, 0);
    }

    float lg[4][4];
#pragma unroll
    for (int mb = 0; mb < 4; mb++) {
#pragma unroll
      for (int rr = 0; rr < 4; rr++) {
        float v = sacc[mb][rr] * SC2 - (float)lcur[mb][rr] * lmv2;
        if (masked) {
          int mcol = m0 + mb * 16 + mq + rr;
          v = (mcol < mlimit) ? v : -INFINITY;
        }
        lg[mb][rr] = v;
      }
    }
    float cm = -INFINITY;
#pragma unroll
    for (int mb = 0; mb < 4; mb++)
#pragma unroll
      for (int rr = 0; rr < 4; rr++) cm = fmaxf(cm, lg[mb][rr]);
    cm = fmaxf(cm, __shfl_xor(cm, 16, 64));
    cm = fmaxf(cm, __shfl_xor(cm, 32, 64));

    bool upd = !__all(cm - m_run <= THR2_);
    float corr = 1.0f;
    if (upd) {
      float nm = fmaxf(m_run, cm);
      corr = exp2f(m_run - nm);
      m_run = nm;
      lmvs[qrow] = corr;
    }
    float ps = 0.0f;
#pragma unroll
    for (int mb = 0; mb < 4; mb++) {
      f16x4 p4;
#pragma unroll
      for (int rr = 0; rr < 4; rr++) {
        float p = exp2f(lg[mb][rr] - m_run);
        ps += p;
        p4[rr] = (_Float16)p;
      }
      *(f16x4*)&QP[qrow * LQP_ + mb * 16 + mq] = p4;
    }
    if (upd) {
      float4 c4 = *(const float4*)&lmvs[w16 + mq];
      s_part = s_part * corr + ps;
      oacc[0][0] *= c4.x; oacc[0][1] *= c4.y; oacc[0][2] *= c4.z; oacc[0][3] *= c4.w;
      oacc[1][0] *= c4.x; oacc[1][1] *= c4.y; oacc[1][2] *= c4.z; oacc[1][3] *= c4.w;
    } else {
      s_part += ps;
    }

#pragma unroll
    for (int ks = 0; ks < 2; ks++) {
      f16x8 pa = *(const f16x8*)&QP[(w16 + lr) * LQP_ + ks * 32 + lk];
#pragma unroll
      for (int db = 0; db < 2; db++) {
        f16x8 vf = *(const f16x8*)&Vs[cur][(db * 16 + lr) * LQP_ + ks * 32 + lk];
        oacc[db] = __builtin_amdgcn_mfma_f32_16x16x32_f16(pa, vf, oacc[db], 0, 0, 0);
      }
    }
  };

  for (int c = 0; c < NCHUNK2_ - 1; c++) chunk_body(c, false);
  chunk_body(NCHUNK2_ - 1, true);

  float st = s_part;
  st += __shfl_xor(st, 16, 64);
  st += __shfl_xor(st, 32, 64);

  size_t base = (size_t)(half * 40 + ih) * A_;
  if (lane < 16) {
    int a = a0 + w16 + lane;
    if (a < A_) {
      part_ms[(base + a) * 2 + 0] = m_run;
      part_ms[(base + a) * 2 + 1] = st;
    }
  }
#pragma unroll
  for (int r = 0; r < 4; r++) {
    int a = a0 + w16 + mq + r;
    if (a < A_) {
      size_t rowb = base + a;
      part_o[rowb * 32 + lr] = oacc[0][r];
      part_o[rowb * 32 + 16 + lr] = oacc[1][r];
    }
  }
}

// ---------------- attention merge (exp2 domain) ----------------
__global__ __launch_bounds__(256) void attn_merge(const float* __restrict__ part_ms,
                                                  const float* __restrict__ part_o,
                                                  _Float16* __restrict__ att16) {
  int t = threadIdx.x;
  int R = blockIdx.x * 8 + (t >> 5);
  int d = t & 31;
  int ih = R / A_, a = R % A_;
  int i = ih >> 3, h = ih & 7;
  size_t r0 = (size_t)ih * A_ + a;
  size_t r1 = (size_t)(40 + ih) * A_ + a;
  float m0 = part_ms[r0 * 2], s0 = part_ms[r0 * 2 + 1];
  float m1 = part_ms[r1 * 2], s1 = part_ms[r1 * 2 + 1];
  float M = fmaxf(m0, m1);
  float e0 = exp2f(m0 - M), e1 = exp2f(m1 - M);
  float inv = 1.0f / (s0 * e0 + s1 * e1);
  float o = part_o[r0 * 32 + d] * e0 + part_o[r1 * 32 + d] * e1;
  att16[((size_t)(i * A_ + a)) * D_ + h * DH_ + d] = (_Float16)(o * inv);
}

// ---------------- LayerNorm (fused outp split-K reduce + bias + residual) ----------------
__global__ __launch_bounds__(256) void ln_kernel(const float* __restrict__ partial2,
                                                 const float* __restrict__ bo,
                                                 const float* __restrict__ resid,
                                                 const float* __restrict__ g,
                                                 const float* __restrict__ b,
                                                 float* __restrict__ out) {
  int row = blockIdx.x;
  int t = threadIdx.x;
  size_t idx = (size_t)row * D_ + t;
  float v = partial2[idx] + partial2[(size_t)4500 * D_ + idx] + bo[t] + resid[idx];
  float s = v, sq = v * v;
#pragma unroll
  for (int o = 32; o; o >>= 1) {
    s += __shfl_xor(s, o, 64);
    sq += __shfl_xor(sq, o, 64);
  }
  __shared__ float ss[4], ssq[4];
  int wid = t >> 6, lane = t & 63;
  if (lane == 0) { ss[wid] = s; ssq[wid] = sq; }
  __syncthreads();
  float ts = ss[0] + ss[1] + ss[2] + ss[3];
  float tq = ssq[0] + ssq[1] + ssq[2] + ssq[3];
  float mean = ts / (float)D_;
  float var = tq / (float)D_ - mean * mean;
  out[idx] = (v - mean) * rsqrtf(var + 1e-5f) * g[t] + b[t];
}

extern "C" void kernel_launch(void* const* d_in, const int* in_sizes, int n_in,
                              void* d_out, int out_size, void* d_ws, size_t ws_size,
                              hipStream_t stream) {
  const float* i2j_anchor   = (const float*)d_in[0];
  const float* b_anchor     = (const float*)d_in[1];
  const float* b_feature    = (const float*)d_in[2];
  const float* tm           = (const float*)d_in[3];
  const float* anchor_embed = (const float*)d_in[4];
  const float* w_roi  = (const float*)d_in[5];
  const float* b_roi  = (const float*)d_in[6];
  const float* bn_g   = (const float*)d_in[7];
  const float* bn_b   = (const float*)d_in[8];
  const float* fc1_w  = (const float*)d_in[9];
  const float* fc1_b  = (const float*)d_in[10];
  const float* fc2_w  = (const float*)d_in[11];
  const float* fc2_b  = (const float*)d_in[12];
  const float* anc_w  = (const float*)d_in[13];
  const float* anc_b  = (const float*)d_in[14];
  const float* lam_w  = (const float*)d_in[15];
  const float* lam_b  = (const float*)d_in[16];
  const float* wq = (const float*)d_in[17];
  const float* bq = (const float*)d_in[18];
  const float* wk = (const float*)d_in[19];
  const float* bk = (const float*)d_in[20];
  const float* wv = (const float*)d_in[21];
  const float* bv = (const float*)d_in[22];
  const float* wo = (const float*)d_in[23];
  const float* bo = (const float*)d_in[24];
  const float* ln_g = (const float*)d_in[25];
  const float* ln_b = (const float*)d_in[26];

  float* ws = (float*)d_ws;
  size_t off = 0;
  auto alloc = [&](size_t n) { float* p = ws + off; off += (n + 3) & ~(size_t)3; return p; };

  float* scores     = alloc(N_ * A_);
  int*   top_idx    = (int*)alloc(N_ * K_);
  float* conf       = alloc(N_ * K_);
  float* t_mlp      = alloc(20 * D_);
  float* conf_rm    = alloc((size_t)N_ * M_);
  float* i2j_rm     = alloc((size_t)N_ * M_ * AD_);
  _Float16* key_feat16 = (_Float16*)alloc((size_t)N_ * M_ * D_ / 2);
  _Float16* key_in16   = (_Float16*)alloc((size_t)N_ * M_ * D_ / 2);
  _Float16* kT16       = (_Float16*)alloc((size_t)N_ * D_ * M_ / 2);
  _Float16* inside16   = (_Float16*)alloc((size_t)N_ * A_ * M_ / 2);
  _Float16* wT16       = (_Float16*)alloc((size_t)4 * D_ * D_ / 2);
  _Float16* Lbuf16     = (_Float16*)alloc((size_t)N_ * A_ * MP_ / 2 + 16);
  float* partial    = alloc((size_t)4 * N_ * A_ * D_);
  float* bf_upd     = alloc((size_t)N_ * A_ * D_);
  _Float16* qin16   = (_Float16*)alloc((size_t)N_ * A_ * D_ / 2);
  _Float16* qh16    = (_Float16*)alloc((size_t)N_ * A_ * D_ / 2);
  _Float16* kh16    = (_Float16*)alloc((size_t)N_ * M_ * D_ / 2);
  _Float16* vhT16   = (_Float16*)alloc((size_t)N_ * D_ * MP_ / 2 + 16);
  float* lm_rm      = alloc((size_t)N_ * A_ * H_);
  _Float16* att16   = (_Float16*)alloc((size_t)N_ * A_ * D_ / 2);
  float* partial2   = alloc((size_t)2 * N_ * A_ * D_);
  float* part_ms    = alloc((size_t)2 * 40 * A_ * 2);
  float* part_o     = alloc((size_t)2 * 40 * A_ * 32);

  // 1. fused scores + tiny MLP (1125 score blocks + 20 MLP blocks)
  scoremlp_kernel<<<SCOREB_ + 20, 256, 0, stream>>>(b_feature, w_roi, b_roi, tm,
                                                    bn_g, bn_b, fc1_w, fc1_b, fc2_w, fc2_b,
                                                    scores, t_mlp);
  // 2. top-k
  topk_kernel<<<N_, 1024, 0, stream>>>(scores, top_idx, conf);
  // 3. gather
  gather_kernel<<<dim3(N_ * NM1_, K_ / GKT_), 256, 0, stream>>>(b_feature, i2j_anchor, top_idx, conf,
                                                                anc_w, anc_b, t_mlp,
                                                                key_feat16, conf_rm, i2j_rm, key_in16);
  // 4. fused transposes
  trans_kernel<<<64 + 380, 256, 0, stream>>>(wq, wk, wv, wo, key_feat16, wT16, kT16);
  // 5. fused inside mask + bias table
  insbias_kernel<<<dim3(N_, A_ / 4), 256, 0, stream>>>(i2j_rm, conf_rm, b_anchor, inside16, Lbuf16);
  // 6. agg GEMM split-K
  agg_kernel<<<dim3(15, 4, N_ * 4), 256, 0, stream>>>(inside16, kT16, partial);
  // 7. reduce + qin + lam
  agg_reduce<<<(N_ * A_) / 4, 256, 0, stream>>>(partial, b_feature, anchor_embed, lam_w, lam_b,
                                                bf_upd, qin16, lm_rm);
  // 8. fused q/k/v projections
  qkv_kernel<<<284 + 376 + 376, 256, 0, stream>>>(qin16, key_in16, key_feat16, wT16,
                                                  bq, bk, bv, qh16, kh16, vhT16);
  // 9. attention (double-buffered, 1 barrier/chunk)
  attn_mfma<<<1200, 256, 0, stream>>>(qh16, kh16, vhT16, lm_rm, Lbuf16, part_ms, part_o);
  // 10. merge halves
  attn_merge<<<(40 * A_) / 8, 256, 0, stream>>>(part_ms, part_o, att16);
  // 11. out projection split-K x2
  outp_kernel<<<568, 256, 0, stream>>>(att16, wT16 + 3 * D_ * D_, partial2);
  // 12. LayerNorm
  ln_kernel<<<N_ * A_, 256, 0, stream>>>(partial2, bo, bf_upd, ln_g, ln_b, (float*)d_out);
}

// Round 19
// 170.212 us; speedup vs baseline: 1.0451x; 1.0200x over previous
//
#include <hip/hip_runtime.h>
#include <math.h>

#define N_ 5
#define A_ 900
#define AD_ 8
#define D_ 256
#define H_ 8
#define DH_ 32
#define K_ 300
#define NM1_ 4
#define M_ 1200
#define MP_ 1216
#define KC_ 64
#define HALF_ 600
#define NCHUNK2_ 10
#define SCOREB_ 1125

typedef _Float16 f16x8 __attribute__((ext_vector_type(8)));
typedef _Float16 f16x4 __attribute__((ext_vector_type(4)));
typedef float f32x4 __attribute__((ext_vector_type(4)));

#define LOG2E_ 1.4426950408889634f

// ---------------- fused scores + tiny MLP + weight transpose ----------------
// blocks [0,1125): scores; [1125,1145): MLP; [1145,1209): wtrans
__global__ __launch_bounds__(256) void scoremlp_kernel(const float* __restrict__ bf,
                                                       const float* __restrict__ w,
                                                       const float* __restrict__ b,
                                                       const float* __restrict__ tm,
                                                       const float* __restrict__ bn_g, const float* __restrict__ bn_b,
                                                       const float* __restrict__ fc1_w, const float* __restrict__ fc1_b,
                                                       const float* __restrict__ fc2_w, const float* __restrict__ fc2_b,
                                                       const float* __restrict__ w0, const float* __restrict__ w1,
                                                       const float* __restrict__ w2, const float* __restrict__ w3,
                                                       float* __restrict__ scores,
                                                       float* __restrict__ t_out,
                                                       _Float16* __restrict__ wT) {
  __shared__ __align__(16) char smem[64 * 65 * 4];
  int bid = blockIdx.x;
  int t = threadIdx.x;
  if (bid < SCOREB_) {
    int wid = t >> 6, lane = t & 63;
    int row = bid * 4 + wid;
    if (row >= N_ * A_) return;
    const float* x = bf + (long)row * D_;
    float dot = 0.f;
#pragma unroll
    for (int e = 0; e < 4; e++) dot += x[lane + 64 * e] * w[lane + 64 * e];
#pragma unroll
    for (int o = 32; o; o >>= 1) dot += __shfl_xor(dot, o, 64);
    if (lane == 0) scores[row] = dot + b[0];
  } else if (bid < SCOREB_ + 20) {
    int r = bid - SCOREB_;
    float* x2 = (float*)smem;        // [20][12]
    float* y2 = x2 + 240;            // [12]
    float* hbuf = y2 + 12;           // [256]
    if (t < 240) {
      int rr = t / 12, f = t % 12;
      int i = rr / NM1_, jj = rr % NM1_;
      int j = jj < i ? jj : jj + 1;
      x2[rr * 12 + f] = tm[((long)(i * N_ + j) * 4 + (f / 4)) * 4 + (f % 4)];
    }
    __syncthreads();
    if (t < 12) {
      float s = 0.f;
      for (int rr = 0; rr < 20; rr++) s += x2[rr * 12 + t];
      float m = s / 20.0f;
      float v = 0.f;
      for (int rr = 0; rr < 20; rr++) { float d = x2[rr * 12 + t] - m; v += d * d; }
      v /= 20.0f;
      y2[t] = (x2[r * 12 + t] - m) * rsqrtf(v + 1e-5f) * bn_g[t] + bn_b[t];
    }
    __syncthreads();
    float acc = fc1_b[t];
#pragma unroll
    for (int f = 0; f < 12; f++) acc += y2[f] * fc1_w[f * D_ + t];
    hbuf[t] = fmaxf(acc, 0.0f);
    __syncthreads();
    float acc2 = fc2_b[t];
    for (int k = 0; k < D_; k++) acc2 += hbuf[k] * fc2_w[k * D_ + t];
    t_out[r * D_ + t] = acc2;
  } else {
    int wb = bid - (SCOREB_ + 20);
    int y = wb >> 4, tile = wb & 15;
    const float* src = (y == 0) ? w0 : (y == 1) ? w1 : (y == 2) ? w2 : w3;
    _Float16* dst = wT + (size_t)y * D_ * D_;
    int kr = (tile >> 2) * 64, nc = (tile & 3) * 64;
    float* lds = (float*)smem;  // [64][65]
#pragma unroll
    for (int r = 0; r < 16; r++) {
      int row = r * 4 + (t >> 6), col = t & 63;
      lds[row * 65 + col] = src[(size_t)(kr + row) * D_ + nc + col];
    }
    __syncthreads();
#pragma unroll
    for (int r = 0; r < 16; r++) {
      int orow = r * 4 + (t >> 6), ocol = t & 63;
      dst[(size_t)(nc + orow) * D_ + kr + ocol] = (_Float16)lds[ocol * 65 + orow];
    }
  }
}

// ---------------- top-k ----------------
__global__ __launch_bounds__(1024) void topk_kernel(const float* __restrict__ scores,
                                                    int* __restrict__ top_idx,
                                                    float* __restrict__ conf) {
  __shared__ float sc[1024];
  __shared__ int si[1024];
  int i = blockIdx.x, t = threadIdx.x;
  sc[t] = (t < A_) ? scores[i * A_ + t] : -INFINITY;
  si[t] = t;
  __syncthreads();
  for (int k = 2; k <= 1024; k <<= 1) {
    for (int j = k >> 1; j > 0; j >>= 1) {
      int ixj = t ^ j;
      if (ixj > t) {
        bool dir = ((t & k) == 0);
        float a = sc[t], b = sc[ixj];
        bool sw = dir ? (a < b) : (a > b);
        if (sw) {
          sc[t] = b; sc[ixj] = a;
          int tmp = si[t]; si[t] = si[ixj]; si[ixj] = tmp;
        }
      }
      __syncthreads();
    }
  }
  if (t < K_) {
    top_idx[i * K_ + t] = si[t];
    conf[i * K_ + t] = sc[t] > 0.0f ? 1.0f : 0.0f;
  }
}

// ---------------- gather ----------------
#define GKT_ 10
__global__ __launch_bounds__(256) void gather_kernel(const float* __restrict__ b_feature,
                                                     const float* __restrict__ i2j_anchor,
                                                     const int* __restrict__ top_idx,
                                                     const float* __restrict__ conf,
                                                     const float* __restrict__ anc_w,
                                                     const float* __restrict__ anc_b,
                                                     const float* __restrict__ t_mlp,
                                                     _Float16* __restrict__ key_feat16,
                                                     float* __restrict__ conf_rm,
                                                     float* __restrict__ i2j_rm,
                                                     _Float16* __restrict__ key_in16) {
  int blk = blockIdx.x;
  int i = blk / NM1_, jj = blk % NM1_;
  int j = jj < i ? jj : jj + 1;
  int k0 = blockIdx.y * GKT_;
  int c = threadIdx.x;
  __shared__ float aw[AD_][D_];
#pragma unroll
  for (int r = 0; r < AD_; r++) aw[r][c] = anc_w[r * D_ + c];
  float ab = anc_b[c];
  float tv = t_mlp[(i * NM1_ + jj) * D_ + c];
  __syncthreads();
  for (int k = k0; k < k0 + GKT_; k++) {
    int idx = top_idx[j * K_ + k];
    float cf = conf[j * K_ + k];
    const float* src = b_feature + ((long)(j * A_ + idx)) * D_;
    float val = src[c];
    long mrow = (long)i * M_ + jj * K_ + k;
    key_feat16[mrow * D_ + c] = (_Float16)val;
    const float* ap = i2j_anchor + ((long)((i * N_ + j) * A_ + idx)) * AD_;
    if (c < AD_) i2j_rm[mrow * AD_ + c] = ap[c];
    if (c == 0) conf_rm[mrow] = cf;
    float pos = ab + tv;
#pragma unroll
    for (int r = 0; r < AD_; r++) pos += ap[r] * aw[r][c];
    key_in16[mrow * D_ + c] = (_Float16)(val + pos);
  }
}

// ---------------- fused inside+bias (blocks 0..1124) + key_feat transpose (1125..1504) ----------------
__global__ __launch_bounds__(256) void insbias_kernel(const float* __restrict__ i2j_rm,
                                                      const float* __restrict__ conf_rm,
                                                      const float* __restrict__ ban,
                                                      const _Float16* __restrict__ kf,
                                                      _Float16* __restrict__ inside,
                                                      _Float16* __restrict__ Lbuf,
                                                      _Float16* __restrict__ kT) {
  __shared__ __align__(16) char smem[4 * M_ * 4];
  int bid = blockIdx.x;
  if (bid < SCOREB_) {
    int i = bid / 225;
    int g = bid % 225;
    float* cx = (float*)smem;
    float* cy = cx + M_;
    float* cz = cy + M_;
    float* cf = cz + M_;
    for (int m = threadIdx.x; m < M_; m += 256) {
      const float* cp = i2j_rm + ((long)i * M_ + m) * AD_;
      cx[m] = cp[0]; cy[m] = cp[1]; cz[m] = cp[2];
      cf[m] = conf_rm[(long)i * M_ + m];
    }
    __syncthreads();
#pragma unroll
    for (int r = 0; r < 4; r++) {
      int a = g * 4 + r;
      int row = i * A_ + a;
      const float* ap = ban + (long)row * AD_;
      float ax = ap[0], ay = ap[1], az = ap[2];
      float w = expf(ap[3]), l = expf(ap[4]), hh = expf(ap[5]);
      float yaw = atan2f(ap[6], ap[7]);
      float ca = fabsf(cosf(yaw)), sa = fabsf(sinf(yaw));
      float ex = 0.5f * (l * ca + w * sa);
      float ey = 0.5f * (l * sa + w * ca);
      float ez = 0.5f * hh;
      float mn0 = ax - ex, mn1 = ay - ey, mn2 = az - ez;
      float mx0 = ax + ex, mx1 = ay + ey, mx2 = az + ez;
      _Float16* ldst = Lbuf + (size_t)row * MP_;
      _Float16* idst = inside + (size_t)row * M_;
      for (int m = threadIdx.x; m < M_; m += 256) {
        float c0 = cx[m], c1 = cy[m], c2 = cz[m];
        bool ins = (c0 >= mn0) && (c0 <= mx0) && (c1 >= mn1) && (c1 <= mx1) && (c2 >= mn2) && (c2 <= mx2);
        idst[m] = ins ? (_Float16)cf[m] : (_Float16)0.0f;
        float dx = ax - c0, dy = ay - c1;
        ldst[m] = (_Float16)log1pf(sqrtf(dx * dx + dy * dy + 1e-12f));
      }
    }
  } else {
    int b = bid - SCOREB_;
    int i = b / 76, rem = b % 76;
    int m0 = (rem % 19) * 64, d0 = (rem / 19) * 64;
    int t = threadIdx.x;
    _Float16* lds2 = (_Float16*)smem;  // [64][66]
    const _Float16* src = kf + (size_t)i * M_ * D_;
    _Float16* dst = kT + (size_t)i * D_ * M_;
#pragma unroll
    for (int r = 0; r < 16; r++) {
      int row = r * 4 + (t >> 6), col = t & 63;
      int m = m0 + row;
      lds2[row * 66 + col] = (m < M_) ? src[(size_t)m * D_ + d0 + col] : (_Float16)0.0f;
    }
    __syncthreads();
#pragma unroll
    for (int r = 0; r < 16; r++) {
      int orow = r * 4 + (t >> 6), ocol = t & 63;
      int m = m0 + ocol;
      if (m < M_) dst[(size_t)(d0 + orow) * M_ + m] = lds2[ocol * 66 + orow];
    }
  }
}

// ---------------- shared 64x64 MFMA tile body (templated BK, 16B-aligned LDS rows) ----------------
template <int BK, typename TO, bool HAS_BIAS, bool HAS_RES, bool VTRANS = false>
__device__ __forceinline__ void gemm_tile_body(
    const _Float16* __restrict__ A, int lda, int Mr,
    const _Float16* __restrict__ B, int ldb,
    const float* __restrict__ bias, const float* __restrict__ res,
    TO* __restrict__ C, int ldc,
    int m0, int n0, int k_begin, int k_end) {
  constexpr int GLD = BK + 8;     // 72 or 136 halfs: 144/272B rows, 16B-aligned, <=2-way banks
  constexpr int CPR = BK / 8;     // f16x8 chunks per row
  constexpr int RPP = 256 / CPR;  // rows staged per pass
  constexpr int NL = 64 / RPP;    // passes
  __shared__ _Float16 As[64 * GLD];
  __shared__ _Float16 Bs[64 * GLD];
  int tid = threadIdx.x;
  int lane = tid & 63;
  int wid = tid >> 6;
  int wr = (wid >> 1) * 32, wc = (wid & 1) * 32;
  int lr = lane & 15, lk = (lane >> 4) * 8;
  int srow = tid / CPR;
  int scol = (tid % CPR) * 8;
  f16x8 aR[NL], bR[NL];
  f16x8 zero8 = {};
  auto loadg = [&](int kb) {
#pragma unroll
    for (int r = 0; r < NL; r++) {
      int gm = m0 + srow + r * RPP;
      int gk = kb + scol;
      aR[r] = (gm < Mr && gk < k_end) ? *(const f16x8*)&A[(size_t)gm * lda + gk] : zero8;
      int gn = n0 + srow + r * RPP;
      bR[r] = (gk < k_end) ? *(const f16x8*)&B[(size_t)gn * ldb + gk] : zero8;
    }
  };
  auto store_lds = [&]() {
#pragma unroll
    for (int r = 0; r < NL; r++) {
      *(f16x8*)&As[(srow + r * RPP) * GLD + scol] = aR[r];
      *(f16x8*)&Bs[(srow + r * RPP) * GLD + scol] = bR[r];
    }
  };
  f32x4 acc[2][2] = {};
  int niter = (k_end - k_begin + BK - 1) / BK;
  loadg(k_begin);
  store_lds();
  __syncthreads();
  for (int it = 0; it < niter; ++it) {
    bool more = (it + 1 < niter);
    if (more) loadg(k_begin + (it + 1) * BK);
#pragma unroll
    for (int ks = 0; ks < BK / 32; ks++) {
      f16x8 af[2], bf[2];
#pragma unroll
      for (int mi = 0; mi < 2; mi++) af[mi] = *(const f16x8*)&As[(wr + mi * 16 + lr) * GLD + ks * 32 + lk];
#pragma unroll
      for (int ni = 0; ni < 2; ni++) bf[ni] = *(const f16x8*)&Bs[(wc + ni * 16 + lr) * GLD + ks * 32 + lk];
#pragma unroll
      for (int mi = 0; mi < 2; mi++)
#pragma unroll
        for (int ni = 0; ni < 2; ni++)
          acc[mi][ni] = __builtin_amdgcn_mfma_f32_16x16x32_f16(af[mi], bf[ni], acc[mi][ni], 0, 0, 0);
    }
    __syncthreads();
    if (more) { store_lds(); __syncthreads(); }
  }
  if (VTRANS) {
#pragma unroll
    for (int mi = 0; mi < 2; mi++)
#pragma unroll
      for (int ni = 0; ni < 2; ni++)
#pragma unroll
        for (int rr = 0; rr < 4; rr++) {
          int ml = wr + mi * 16 + (lane >> 4) * 4 + rr;
          int dl = wc + ni * 16 + lr;
          float v = acc[mi][ni][rr];
          if (HAS_BIAS) v += bias[n0 + dl];
          As[dl * 72 + ml] = (_Float16)v;
        }
    __syncthreads();
    int dl = tid >> 2, mp = (tid & 3) * 16;
    int gd = n0 + dl;
#pragma unroll
    for (int e8 = 0; e8 < 2; e8++) {
      int gm = m0 + mp + e8 * 8;
      if (gm < Mr) {
        int ii = gm / M_, mm = gm - ii * M_;
        *(f16x8*)&((_Float16*)C)[(size_t)(ii * D_ + gd) * ldc + mm] =
            *(const f16x8*)&As[dl * 72 + mp + e8 * 8];
      }
    }
    return;
  }
#pragma unroll
  for (int mi = 0; mi < 2; mi++)
#pragma unroll
    for (int ni = 0; ni < 2; ni++)
#pragma unroll
      for (int rr = 0; rr < 4; rr++) {
        int row = m0 + wr + mi * 16 + (lane >> 4) * 4 + rr;
        int col = n0 + wc + ni * 16 + lr;
        if (row < Mr) {
          float v = acc[mi][ni][rr];
          if (HAS_BIAS) v += bias[col];
          if (HAS_RES) v += res[(size_t)row * ldc + col];
          C[(size_t)row * ldc + col] = (TO)v;
        }
      }
}

// ---------------- agg GEMM split-K ----------------
__global__ __launch_bounds__(256) void agg_kernel(const _Float16* __restrict__ inside16,
                                                  const _Float16* __restrict__ kT16,
                                                  float* __restrict__ partial) {
  int i = blockIdx.z >> 2, sk = blockIdx.z & 3;
  int kb = sk * 320;
  int ke = kb + 320 < M_ ? kb + 320 : M_;
  gemm_tile_body<64, float, false, false>(
      inside16 + (size_t)i * A_ * M_, M_, A_,
      kT16 + (size_t)i * D_ * M_, M_,
      nullptr, nullptr,
      partial + (size_t)(sk * N_ + i) * A_ * D_, D_,
      blockIdx.x * 64, blockIdx.y * 64, kb, ke);
}

// ---------------- agg reduce + q-input prep + lam projection ----------------
__global__ __launch_bounds__(256) void agg_reduce(const float* __restrict__ partial,
                                                  const float* __restrict__ b_feature,
                                                  const float* __restrict__ anchor_embed,
                                                  const float* __restrict__ lam_w,
                                                  const float* __restrict__ lam_b,
                                                  float* __restrict__ bf_upd,
                                                  _Float16* __restrict__ qin16,
                                                  float* __restrict__ lm_rm) {
  int wid = threadIdx.x >> 6, lane = threadIdx.x & 63;
  int rg = blockIdx.x * 4 + wid;
  int d0 = lane * 4;
  float lw[4][8];
#pragma unroll
  for (int e = 0; e < 4; e++) {
#pragma unroll
    for (int h = 0; h < 8; h++) lw[e][h] = lam_w[(d0 + e) * 8 + h];
  }
  float4 s = *(const float4*)&partial[(size_t)rg * D_ + d0];
#pragma unroll
  for (int sk = 1; sk < 4; sk++) {
    float4 p = *(const float4*)&partial[((size_t)sk * N_ * A_ + rg) * D_ + d0];
    s.x += p.x; s.y += p.y; s.z += p.z; s.w += p.w;
  }
  float4 bf = *(const float4*)&b_feature[(size_t)rg * D_ + d0];
  s.x += bf.x; s.y += bf.y; s.z += bf.z; s.w += bf.w;
  *(float4*)&bf_upd[(size_t)rg * D_ + d0] = s;
  float4 ae = *(const float4*)&anchor_embed[(size_t)rg * D_ + d0];
  f16x4 q4;
  q4[0] = (_Float16)(s.x + ae.x); q4[1] = (_Float16)(s.y + ae.y);
  q4[2] = (_Float16)(s.z + ae.z); q4[3] = (_Float16)(s.w + ae.w);
  *(f16x4*)&qin16[(size_t)rg * D_ + d0] = q4;
  float sv[4] = {s.x, s.y, s.z, s.w};
  float acc[8] = {};
#pragma unroll
  for (int e = 0; e < 4; e++)
#pragma unroll
    for (int h = 0; h < 8; h++) acc[h] += sv[e] * lw[e][h];
#pragma unroll
  for (int h = 0; h < 8; h++) {
#pragma unroll
    for (int o = 32; o; o >>= 1) acc[h] += __shfl_xor(acc[h], o, 64);
  }
  if (lane == 0) {
#pragma unroll
    for (int h = 0; h < 8; h++) lm_rm[(size_t)rg * H_ + h] = acc[h] + lam_b[h];
  }
}

// ---------------- fused q/k/v projections (BK=128; V transposed) ----------------
__global__ __launch_bounds__(256) void qkv_kernel(const _Float16* __restrict__ qA,
                                                  const _Float16* __restrict__ kA,
                                                  const _Float16* __restrict__ vA,
                                                  const _Float16* __restrict__ wT,
                                                  const float* __restrict__ bq,
                                                  const float* __restrict__ bk,
                                                  const float* __restrict__ bv,
                                                  _Float16* __restrict__ qC,
                                                  _Float16* __restrict__ kC,
                                                  _Float16* __restrict__ vT) {
  int bid = blockIdx.x;
  if (bid < 284) {
    int mt = bid % 71, nt = bid / 71;
    gemm_tile_body<128, _Float16, true, false>(qA, D_, 4500, wT, D_, bq, nullptr, qC, D_,
                                               mt * 64, nt * 64, 0, D_);
  } else if (bid < 660) {
    int t = bid - 284;
    int mt = t % 94, nt = t / 94;
    gemm_tile_body<128, _Float16, true, false>(kA, D_, 6000, wT + D_ * D_, D_, bk, nullptr, kC, D_,
                                               mt * 64, nt * 64, 0, D_);
  } else {
    int t = bid - 660;
    int mt = t % 94, nt = t / 94;
    gemm_tile_body<128, _Float16, true, false, true>(vA, D_, 6000, wT + 2 * D_ * D_, D_, bv, nullptr, vT, MP_,
                                                     mt * 64, nt * 64, 0, D_);
  }
}

// ---------------- out projection split-K x2 (BK=128: single iter) ----------------
__global__ __launch_bounds__(256) void outp_kernel(const _Float16* __restrict__ att16,
                                                   const _Float16* __restrict__ woT,
                                                   float* __restrict__ partial2) {
  int bid = blockIdx.x;
  int sk = bid >= 284 ? 1 : 0;
  int t = bid - sk * 284;
  int mt = t % 71, nt = t / 71;
  gemm_tile_body<128, float, false, false>(att16, D_, 4500, woT, D_, nullptr, nullptr,
                                           partial2 + (size_t)sk * 4500 * D_, D_,
                                           mt * 64, nt * 64, sk * 128, sk * 128 + 128);
}

// ---------------- MFMA flash attention: ballot guard, double-buffered, 1 barrier/chunk ----------------
#define LQP_ 72
#define LKS_ 40
#define THR2_ 11.5f
__global__ __launch_bounds__(256) void attn_mfma(const _Float16* __restrict__ qh16,
                                                 const _Float16* __restrict__ kh16,
                                                 const _Float16* __restrict__ vhT,
                                                 const float* __restrict__ lm_rm,
                                                 const _Float16* __restrict__ Lbuf,
                                                 float* __restrict__ part_ms,
                                                 float* __restrict__ part_o) {
  int bid = blockIdx.x;
  int wgid = (bid & 7) * 150 + (bid >> 3);
  int ih = wgid / 30;
  int rest = wgid % 30;
  int half = rest / 15, qt = rest % 15;
  int i = ih >> 3, h = ih & 7;
  int a0 = qt * 64;
  int mbase = half * HALF_;
  int mlimit = mbase + HALF_;

  __shared__ _Float16 QP[64 * LQP_];
  __shared__ _Float16 Ks[2][64 * LKS_];
  __shared__ _Float16 Vs[2][32 * LQP_];
  __shared__ float lmvs[64];

  int tid = threadIdx.x;
  int lane = tid & 63;
  int w16 = (tid >> 6) * 16;
  int lr = lane & 15;
  int lk = (lane >> 4) * 8;
  int mq = (lane >> 4) * 4;
  int srow = tid >> 2, spiece = tid & 3;
  int vrow = tid >> 3, vpc = (tid & 7) * 8;

  {
    int aq = a0 + srow;
    int a_ld = aq < A_ ? aq : A_ - 1;
    const uint4* src = (const uint4*)(qh16 + ((long)(i * A_ + a_ld) * D_ + h * DH_));
    *(uint4*)&QP[srow * LQP_ + spiece * 8] = src[spiece];
  }
  if (tid < 64) {
    int aq = a0 + tid;
    int a_ld = aq < A_ ? aq : A_ - 1;
    lmvs[tid] = lm_rm[(long)(i * A_ + a_ld) * H_ + h];
  }

  int qrow = w16 + lr;
  const _Float16* kb = kh16 + (long)i * M_ * D_ + h * DH_;
  const _Float16* vb = vhT + (size_t)(i * D_ + h * DH_) * MP_;
  const _Float16* lq;
  {
    int aq = a0 + qrow;
    int a_ld = aq < A_ ? aq : A_ - 1;
    lq = Lbuf + (size_t)(i * A_ + a_ld) * MP_ + mq;
  }

  uint4 kvR;
  f16x8 vvR;
  f16x4 lR[4];
  auto loadr = [&](int c) {
    int m0 = mbase + c * KC_;
    int mrow = m0 + srow;
    kvR = (mrow < M_) ? ((const uint4*)(kb + (long)mrow * D_))[spiece] : make_uint4(0, 0, 0, 0);
    vvR = *(const f16x8*)&vb[(size_t)vrow * MP_ + m0 + vpc];
#pragma unroll
    for (int mb = 0; mb < 4; mb++) lR[mb] = *(const f16x4*)&lq[m0 + mb * 16];
  };

  __syncthreads();

  float lmv2 = lmvs[qrow] * LOG2E_;
  f16x8 qa = *(const f16x8*)&QP[qrow * LQP_ + lk];

  float m_run = -INFINITY, s_part = 0.0f;
  f32x4 oacc[2] = {};

  loadr(0);

  const float SC2 = 0.17677669529663687f * LOG2E_;

  auto chunk_body = [&](int c, bool masked) {
    int m0 = mbase + c * KC_;
    int cur = c & 1;
    *(uint4*)&Ks[cur][srow * LKS_ + spiece * 8] = kvR;
    *(f16x8*)&Vs[cur][vrow * LQP_ + vpc] = vvR;
    f16x4 lcur[4];
#pragma unroll
    for (int mb = 0; mb < 4; mb++) lcur[mb] = lR[mb];
    if (c + 1 < NCHUNK2_) loadr(c + 1);
    __syncthreads();

    f32x4 sacc[4];
#pragma unroll
    for (int mb = 0; mb < 4; mb++) {
      f16x8 kf = *(const f16x8*)&Ks[cur][(mb * 16 + lr) * LKS_ + lk];
      sacc[mb] = __builtin_amdgcn_mfma_f32_16x16x32_f16(kf, qa, (f32x4){0.f, 0.f, 0.f, 0.f}, 0, 0, 0);
    }

    float lg[4][4];
#pragma unroll
    for (int mb = 0; mb < 4; mb++) {
#pragma unroll
      for (int rr = 0; rr < 4; rr++) {
        float v = sacc[mb][rr] * SC2 - (float)lcur[mb][rr] * lmv2;
        if (masked) {
          int mcol = m0 + mb * 16 + mq + rr;
          v = (mcol < mlimit) ? v : -INFINITY;
        }
        lg[mb][rr] = v;
      }
    }
    // per-lane max; cross-lane reduce only when an update is needed (ballot guard)
    float cmL = -INFINITY;
#pragma unroll
    for (int mb = 0; mb < 4; mb++)
#pragma unroll
      for (int rr = 0; rr < 4; rr++) cmL = fmaxf(cmL, lg[mb][rr]);

    bool upd = !__all(cmL - m_run <= THR2_);
    float corr = 1.0f;
    if (upd) {
      float cm = fmaxf(cmL, __shfl_xor(cmL, 16, 64));
      cm = fmaxf(cm, __shfl_xor(cm, 32, 64));
      float nm = fmaxf(m_run, cm);
      corr = exp2f(m_run - nm);
      m_run = nm;
      lmvs[qrow] = corr;
    }
    float ps = 0.0f;
#pragma unroll
    for (int mb = 0; mb < 4; mb++) {
      f16x4 p4;
#pragma unroll
      for (int rr = 0; rr < 4; rr++) {
        float p = exp2f(lg[mb][rr] - m_run);
        ps += p;
        p4[rr] = (_Float16)p;
      }
      *(f16x4*)&QP[qrow * LQP_ + mb * 16 + mq] = p4;
    }
    if (upd) {
      float4 c4 = *(const float4*)&lmvs[w16 + mq];
      s_part = s_part * corr + ps;
      oacc[0][0] *= c4.x; oacc[0][1] *= c4.y; oacc[0][2] *= c4.z; oacc[0][3] *= c4.w;
      oacc[1][0] *= c4.x; oacc[1][1] *= c4.y; oacc[1][2] *= c4.z; oacc[1][3] *= c4.w;
    } else {
      s_part += ps;
    }

#pragma unroll
    for (int ks = 0; ks < 2; ks++) {
      f16x8 pa = *(const f16x8*)&QP[(w16 + lr) * LQP_ + ks * 32 + lk];
#pragma unroll
      for (int db = 0; db < 2; db++) {
        f16x8 vf = *(const f16x8*)&Vs[cur][(db * 16 + lr) * LQP_ + ks * 32 + lk];
        oacc[db] = __builtin_amdgcn_mfma_f32_16x16x32_f16(pa, vf, oacc[db], 0, 0, 0);
      }
    }
  };

  for (int c = 0; c < NCHUNK2_ - 1; c++) chunk_body(c, false);
  chunk_body(NCHUNK2_ - 1, true);

  float st = s_part;
  st += __shfl_xor(st, 16, 64);
  st += __shfl_xor(st, 32, 64);

  size_t base = (size_t)(half * 40 + ih) * A_;
  if (lane < 16) {
    int a = a0 + w16 + lane;
    if (a < A_) {
      part_ms[(base + a) * 2 + 0] = m_run;
      part_ms[(base + a) * 2 + 1] = st;
    }
  }
#pragma unroll
  for (int r = 0; r < 4; r++) {
    int a = a0 + w16 + mq + r;
    if (a < A_) {
      size_t rowb = base + a;
      part_o[rowb * 32 + lr] = oacc[0][r];
      part_o[rowb * 32 + 16 + lr] = oacc[1][r];
    }
  }
}

// ---------------- attention merge (exp2 domain) ----------------
__global__ __launch_bounds__(256) void attn_merge(const float* __restrict__ part_ms,
                                                  const float* __restrict__ part_o,
                                                  _Float16* __restrict__ att16) {
  int t = threadIdx.x;
  int R = blockIdx.x * 8 + (t >> 5);
  int d = t & 31;
  int ih = R / A_, a = R % A_;
  int i = ih >> 3, h = ih & 7;
  size_t r0 = (size_t)ih * A_ + a;
  size_t r1 = (size_t)(40 + ih) * A_ + a;
  float m0 = part_ms[r0 * 2], s0 = part_ms[r0 * 2 + 1];
  float m1 = part_ms[r1 * 2], s1 = part_ms[r1 * 2 + 1];
  float M = fmaxf(m0, m1);
  float e0 = exp2f(m0 - M), e1 = exp2f(m1 - M);
  float inv = 1.0f / (s0 * e0 + s1 * e1);
  float o = part_o[r0 * 32 + d] * e0 + part_o[r1 * 32 + d] * e1;
  att16[((size_t)(i * A_ + a)) * D_ + h * DH_ + d] = (_Float16)(o * inv);
}

// ---------------- LayerNorm (fused outp split-K reduce + bias + residual) ----------------
__global__ __launch_bounds__(256) void ln_kernel(const float* __restrict__ partial2,
                                                 const float* __restrict__ bo,
                                                 const float* __restrict__ resid,
                                                 const float* __restrict__ g,
                                                 const float* __restrict__ b,
                                                 float* __restrict__ out) {
  int row = blockIdx.x;
  int t = threadIdx.x;
  size_t idx = (size_t)row * D_ + t;
  float v = partial2[idx] + partial2[(size_t)4500 * D_ + idx] + bo[t] + resid[idx];
  float s = v, sq = v * v;
#pragma unroll
  for (int o = 32; o; o >>= 1) {
    s += __shfl_xor(s, o, 64);
    sq += __shfl_xor(sq, o, 64);
  }
  __shared__ float ss[4], ssq[4];
  int wid = t >> 6, lane = t & 63;
  if (lane == 0) { ss[wid] = s; ssq[wid] = sq; }
  __syncthreads();
  float ts = ss[0] + ss[1] + ss[2] + ss[3];
  float tq = ssq[0] + ssq[1] + ssq[2] + ssq[3];
  float mean = ts / (float)D_;
  float var = tq / (float)D_ - mean * mean;
  out[idx] = (v - mean) * rsqrtf(var + 1e-5f) * g[t] + b[t];
}

extern "C" void kernel_launch(void* const* d_in, const int* in_sizes, int n_in,
                              void* d_out, int out_size, void* d_ws, size_t ws_size,
                              hipStream_t stream) {
  const float* i2j_anchor   = (const float*)d_in[0];
  const float* b_anchor     = (const float*)d_in[1];
  const float* b_feature    = (const float*)d_in[2];
  const float* tm           = (const float*)d_in[3];
  const float* anchor_embed = (const float*)d_in[4];
  const float* w_roi  = (const float*)d_in[5];
  const float* b_roi  = (const float*)d_in[6];
  const float* bn_g   = (const float*)d_in[7];
  const float* bn_b   = (const float*)d_in[8];
  const float* fc1_w  = (const float*)d_in[9];
  const float* fc1_b  = (const float*)d_in[10];
  const float* fc2_w  = (const float*)d_in[11];
  const float* fc2_b  = (const float*)d_in[12];
  const float* anc_w  = (const float*)d_in[13];
  const float* anc_b  = (const float*)d_in[14];
  const float* lam_w  = (const float*)d_in[15];
  const float* lam_b  = (const float*)d_in[16];
  const float* wq = (const float*)d_in[17];
  const float* bq = (const float*)d_in[18];
  const float* wk = (const float*)d_in[19];
  const float* bk = (const float*)d_in[20];
  const float* wv = (const float*)d_in[21];
  const float* bv = (const float*)d_in[22];
  const float* wo = (const float*)d_in[23];
  const float* bo = (const float*)d_in[24];
  const float* ln_g = (const float*)d_in[25];
  const float* ln_b = (const float*)d_in[26];

  float* ws = (float*)d_ws;
  size_t off = 0;
  auto alloc = [&](size_t n) { float* p = ws + off; off += (n + 3) & ~(size_t)3; return p; };

  float* scores     = alloc(N_ * A_);
  int*   top_idx    = (int*)alloc(N_ * K_);
  float* conf       = alloc(N_ * K_);
  float* t_mlp      = alloc(20 * D_);
  float* conf_rm    = alloc((size_t)N_ * M_);
  float* i2j_rm     = alloc((size_t)N_ * M_ * AD_);
  _Float16* key_feat16 = (_Float16*)alloc((size_t)N_ * M_ * D_ / 2);
  _Float16* key_in16   = (_Float16*)alloc((size_t)N_ * M_ * D_ / 2);
  _Float16* kT16       = (_Float16*)alloc((size_t)N_ * D_ * M_ / 2);
  _Float16* inside16   = (_Float16*)alloc((size_t)N_ * A_ * M_ / 2);
  _Float16* wT16       = (_Float16*)alloc((size_t)4 * D_ * D_ / 2);
  _Float16* Lbuf16     = (_Float16*)alloc((size_t)N_ * A_ * MP_ / 2 + 16);
  float* partial    = alloc((size_t)4 * N_ * A_ * D_);
  float* bf_upd     = alloc((size_t)N_ * A_ * D_);
  _Float16* qin16   = (_Float16*)alloc((size_t)N_ * A_ * D_ / 2);
  _Float16* qh16    = (_Float16*)alloc((size_t)N_ * A_ * D_ / 2);
  _Float16* kh16    = (_Float16*)alloc((size_t)N_ * M_ * D_ / 2);
  _Float16* vhT16   = (_Float16*)alloc((size_t)N_ * D_ * MP_ / 2 + 16);
  float* lm_rm      = alloc((size_t)N_ * A_ * H_);
  _Float16* att16   = (_Float16*)alloc((size_t)N_ * A_ * D_ / 2);
  float* partial2   = alloc((size_t)2 * N_ * A_ * D_);
  float* part_ms    = alloc((size_t)2 * 40 * A_ * 2);
  float* part_o     = alloc((size_t)2 * 40 * A_ * 32);

  // 1. fused scores + tiny MLP + weight transpose
  scoremlp_kernel<<<SCOREB_ + 20 + 64, 256, 0, stream>>>(b_feature, w_roi, b_roi, tm,
                                                         bn_g, bn_b, fc1_w, fc1_b, fc2_w, fc2_b,
                                                         wq, wk, wv, wo,
                                                         scores, t_mlp, wT16);
  // 2. top-k
  topk_kernel<<<N_, 1024, 0, stream>>>(scores, top_idx, conf);
  // 3. gather
  gather_kernel<<<dim3(N_ * NM1_, K_ / GKT_), 256, 0, stream>>>(b_feature, i2j_anchor, top_idx, conf,
                                                                anc_w, anc_b, t_mlp,
                                                                key_feat16, conf_rm, i2j_rm, key_in16);
  // 4. fused inside+bias + key_feat transpose
  insbias_kernel<<<SCOREB_ + 380, 256, 0, stream>>>(i2j_rm, conf_rm, b_anchor, key_feat16,
                                                    inside16, Lbuf16, kT16);
  // 5. agg GEMM split-K
  agg_kernel<<<dim3(15, 4, N_ * 4), 256, 0, stream>>>(inside16, kT16, partial);
  // 6. reduce + qin + lam
  agg_reduce<<<(N_ * A_) / 4, 256, 0, stream>>>(partial, b_feature, anchor_embed, lam_w, lam_b,
                                                bf_upd, qin16, lm_rm);
  // 7. fused q/k/v projections (BK=128)
  qkv_kernel<<<284 + 376 + 376, 256, 0, stream>>>(qin16, key_in16, key_feat16, wT16,
                                                  bq, bk, bv, qh16, kh16, vhT16);
  // 8. attention (ballot guard)
  attn_mfma<<<1200, 256, 0, stream>>>(qh16, kh16, vhT16, lm_rm, Lbuf16, part_ms, part_o);
  // 9. merge halves
  attn_merge<<<(40 * A_) / 8, 256, 0, stream>>>(part_ms, part_o, att16);
  // 10. out projection split-K x2 (BK=128, single iter)
  outp_kernel<<<568, 256, 0, stream>>>(att16, wT16 + 3 * D_ * D_, partial2);
  // 11. LayerNorm
  ln_kernel<<<N_ * A_, 256, 0, stream>>>(partial2, bo, bf_upd, ln_g, ln_b, (float*)d_out);
}